// Round 1
// baseline (8802.187 us; speedup 1.0000x reference)
//
#include <hip/hip_runtime.h>
#include <hip/hip_bf16.h>
#include <math.h>

#define T_ 30
#define D_ 256
#define H_ 8
#define DH_ 32
#define HID_ 128
#define TD_ 64
#define SEM_ 320
#define B_ 128
#define C_ 50
#define NN_ 15
#define NU_ 15
#define NSEQ_ (B_*C_ + B_ + B_*NN_)   /* 8448 */

__device__ __forceinline__ unsigned short f2bf(float f) {
    union { float f; unsigned u; } v; v.f = f;
    unsigned u = v.u;
    u += 0x7FFFu + ((u >> 16) & 1u);      // RTNE
    return (unsigned short)(u >> 16);
}
__device__ __forceinline__ float bflo(unsigned p) {
    union { unsigned u; float f; } v; v.u = p << 16; return v.f;
}
__device__ __forceinline__ float bfhi(unsigned p) {
    union { unsigned u; float f; } v; v.u = p & 0xFFFF0000u; return v.f;
}

__device__ __forceinline__ void softmax_ip(float* v, int n) {
    float m = -1e30f;
    for (int i = 0; i < n; ++i) m = fmaxf(m, v[i]);
    float s = 0.f;
    for (int i = 0; i < n; ++i) { float e = __expf(v[i] - m); v[i] = e; s += e; }
    float inv = 1.f / s;
    for (int i = 0; i < n; ++i) v[i] *= inv;
}

// ---------------------------------------------------------------------------
// Transformer: one block per sequence (8448 total).
// ---------------------------------------------------------------------------
__global__ __launch_bounds__(256) void tf_kernel(
    const int* __restrict__ clicked_title, const int* __restrict__ clicked_topic,
    const int* __restrict__ candidate_title, const int* __restrict__ candidate_topic,
    const int* __restrict__ neighbor_title, const int* __restrict__ neighbor_topic,
    const float* __restrict__ word_emb, const float* __restrict__ topic_emb,
    const float* __restrict__ Wq, const float* __restrict__ Wk, const float* __restrict__ Wv,
    const float* __restrict__ aW1, const float* __restrict__ ab1, const float* __restrict__ aw2,
    float* __restrict__ out)
{
    __shared__ unsigned xs2[T_][D_/2];      // x as packed bf16 pairs: 15360 B
    __shared__ float os[T_][D_];            // attention output: 30720 B
    __shared__ float qs[T_][DH_+1];         // padded stride 33
    __shared__ float ks[T_][DH_+1];
    __shared__ float vs[T_][DH_+1];
    __shared__ float ss[T_][T_+3];          // scores, stride 33
    __shared__ float pls[T_], pas[T_];
    __shared__ int   toks[T_];

    const int tid = threadIdx.x;
    const int i = blockIdx.x;
    const int* tok; int topic;
    if (i < B_*C_)            { tok = clicked_title   + i*T_;               topic = clicked_topic[i]; }
    else if (i < B_*C_ + B_)  { int j = i - B_*C_;      tok = candidate_title + j*T_; topic = candidate_topic[j]; }
    else                      { int j = i - (B_*C_+B_); tok = neighbor_title  + j*T_; topic = neighbor_topic[j]; }

    if (tid < T_) toks[tid] = tok[tid];
    __syncthreads();

    for (int idx = tid; idx < T_*(D_/2); idx += 256) {
        int r = idx >> 7, dp = idx & 127;
        const float* row = word_emb + (size_t)toks[r] * D_;
        float f0 = row[2*dp], f1 = row[2*dp + 1];
        xs2[r][dp] = (unsigned)f2bf(f0) | ((unsigned)f2bf(f1) << 16);
    }

    const float scale = 0.17677669529663687f;   // 1/sqrt(32)
    for (int h = 0; h < H_; ++h) {
        __syncthreads();   // x ready (1st iter) / prev head's o done (later iters)
        const int col0 = h * DH_;
        const int c = tid & 31, r0 = tid >> 5;   // r0 in 0..7
        for (int which = 0; which < 3; ++which) {
            const float* W = (which == 0) ? Wq : (which == 1 ? Wk : Wv);
            const float* Wc = W + col0 + c;
            float a0 = 0.f, a1 = 0.f, a2 = 0.f, a3 = 0.f;
            for (int dp = 0; dp < D_/2; ++dp) {
                float w0 = Wc[(2*dp) * D_];
                float w1 = Wc[(2*dp + 1) * D_];
                unsigned p0 = xs2[r0][dp];
                unsigned p1 = xs2[r0+8][dp];
                unsigned p2 = xs2[r0+16][dp];
                a0 += bflo(p0)*w0 + bfhi(p0)*w1;
                a1 += bflo(p1)*w0 + bfhi(p1)*w1;
                a2 += bflo(p2)*w0 + bfhi(p2)*w1;
                if (r0 < 6) {
                    unsigned p3 = xs2[r0+24][dp];
                    a3 += bflo(p3)*w0 + bfhi(p3)*w1;
                }
            }
            if (which == 0) {
                qs[r0][c]=a0; qs[r0+8][c]=a1; qs[r0+16][c]=a2; if (r0<6) qs[r0+24][c]=a3;
            } else if (which == 1) {
                ks[r0][c]=a0; ks[r0+8][c]=a1; ks[r0+16][c]=a2; if (r0<6) ks[r0+24][c]=a3;
            } else {
                vs[r0][c]=a0; vs[r0+8][c]=a1; vs[r0+16][c]=a2; if (r0<6) vs[r0+24][c]=a3;
            }
        }
        __syncthreads();
        for (int idx = tid; idx < T_*T_; idx += 256) {
            int r = idx / T_, cc = idx - r*T_;
            float acc = 0.f;
            #pragma unroll
            for (int d = 0; d < DH_; ++d) acc += qs[r][d] * ks[cc][d];
            ss[r][cc] = acc * scale;
        }
        __syncthreads();
        if (tid < T_) {
            float m = -1e30f;
            for (int cc = 0; cc < T_; ++cc) m = fmaxf(m, ss[tid][cc]);
            float sum = 0.f;
            for (int cc = 0; cc < T_; ++cc) { float e = __expf(ss[tid][cc] - m); ss[tid][cc] = e; sum += e; }
            float inv = 1.f / sum;
            for (int cc = 0; cc < T_; ++cc) ss[tid][cc] *= inv;
        }
        __syncthreads();
        for (int idx = tid; idx < T_*DH_; idx += 256) {
            int r = idx >> 5, cc = idx & 31;
            float acc = 0.f;
            #pragma unroll
            for (int k = 0; k < T_; ++k) acc += ss[r][k] * vs[k][cc];
            os[r][col0 + cc] = acc;
        }
    }
    __syncthreads();

    // additive attention pooling: pl = tanh(o @ aW1 + ab1) @ aw2
    const int wid = tid >> 6, lane = tid & 63;
    for (int r = wid; r < T_; r += 4) {
        float a0 = ab1[lane], a1 = ab1[lane + 64];
        for (int d = 0; d < D_; ++d) {
            float xv = os[r][d];
            a0 += xv * aW1[d*HID_ + lane];
            a1 += xv * aW1[d*HID_ + lane + 64];
        }
        float v = tanhf(a0)*aw2[lane] + tanhf(a1)*aw2[lane + 64];
        #pragma unroll
        for (int off = 32; off > 0; off >>= 1) v += __shfl_down(v, off);
        if (lane == 0) pls[r] = v;
    }
    __syncthreads();
    if (tid == 0) {
        float m = -1e30f;
        for (int r = 0; r < T_; ++r) m = fmaxf(m, pls[r]);
        float sum = 0.f;
        for (int r = 0; r < T_; ++r) { float e = __expf(pls[r] - m); pas[r] = e; sum += e; }
        float inv = 1.f / sum;
        for (int r = 0; r < T_; ++r) pas[r] *= inv;
    }
    __syncthreads();
    {
        float acc = 0.f;
        for (int r = 0; r < T_; ++r) acc += pas[r] * os[r][tid];
        out[(size_t)i*SEM_ + tid] = acc;
    }
    if (tid < TD_) out[(size_t)i*SEM_ + D_ + tid] = topic_emb[(size_t)topic*TD_ + tid];
}

// ---------------------------------------------------------------------------
// User branch: clk agg (C=50, dim 320) + user-neighbor agg (Nu=15, dim 128)
// ---------------------------------------------------------------------------
__global__ __launch_bounds__(256) void user_kernel(
    const float* __restrict__ clk_sem,
    const int* __restrict__ clicked_mask,
    const int* __restrict__ user_id,
    const int* __restrict__ neighbor_users,
    const int* __restrict__ neighbor_user_mask,
    const float* __restrict__ user_emb,
    const float* __restrict__ clk_W1, const float* __restrict__ clk_b1,
    const float* __restrict__ clk_w2, const float* __restrict__ clk_b2,
    const float* __restrict__ uagg_W1, const float* __restrict__ uagg_b1,
    const float* __restrict__ uagg_w2, const float* __restrict__ uagg_b2,
    float* __restrict__ out)
{
    const int b = blockIdx.x;
    const int tid = threadIdx.x, wid = tid >> 6, lane = tid & 63;
    __shared__ float lc[C_], lu[NU_];

    for (int c0 = wid; c0 < C_; c0 += 4) {
        if (clicked_mask[b*C_ + c0] != 0) {
            const float* x = clk_sem + ((size_t)b*C_ + c0) * SEM_;
            float a0 = clk_b1[lane], a1 = clk_b1[lane + 64];
            for (int d = 0; d < SEM_; ++d) {
                float xv = x[d];
                a0 += xv * clk_W1[d*HID_ + lane];
                a1 += xv * clk_W1[d*HID_ + lane + 64];
            }
            float v = tanhf(a0)*clk_w2[lane] + tanhf(a1)*clk_w2[lane + 64];
            #pragma unroll
            for (int off = 32; off > 0; off >>= 1) v += __shfl_down(v, off);
            if (lane == 0) lc[c0] = v + clk_b2[0];
        } else if (lane == 0) lc[c0] = -1e30f;
    }
    for (int n0 = wid; n0 < NU_; n0 += 4) {
        if (neighbor_user_mask[b*NU_ + n0] != 0) {
            const float* x = user_emb + (size_t)neighbor_users[b*NU_ + n0] * 128;
            float a0 = uagg_b1[lane], a1 = uagg_b1[lane + 64];
            for (int d = 0; d < 128; ++d) {
                float xv = x[d];
                a0 += xv * uagg_W1[d*HID_ + lane];
                a1 += xv * uagg_W1[d*HID_ + lane + 64];
            }
            float v = tanhf(a0)*uagg_w2[lane] + tanhf(a1)*uagg_w2[lane + 64];
            #pragma unroll
            for (int off = 32; off > 0; off >>= 1) v += __shfl_down(v, off);
            if (lane == 0) lu[n0] = v + uagg_b2[0];
        } else if (lane == 0) lu[n0] = -1e30f;
    }
    __syncthreads();
    if (tid == 0) softmax_ip(lc, C_);
    else if (tid == 64) softmax_ip(lu, NU_);
    __syncthreads();

    for (int d = tid; d < SEM_; d += 256) {
        float acc = 0.f;
        for (int c = 0; c < C_; ++c) acc += lc[c] * clk_sem[((size_t)b*C_ + c)*SEM_ + d];
        out[(size_t)b*576 + d] = acc;
    }
    if (tid < 128) {
        out[(size_t)b*576 + 320 + tid] = user_emb[(size_t)user_id[b]*128 + tid];
        float acc = 0.f;
        for (int n = 0; n < NU_; ++n) acc += lu[n] * user_emb[(size_t)neighbor_users[b*NU_ + n]*128 + tid];
        out[(size_t)b*576 + 448 + tid] = acc;
    }
}

// ---------------------------------------------------------------------------
// News branch: nid agg (dim 128) + nsem agg (dim 320) + concat + proj 896->576
// ---------------------------------------------------------------------------
__global__ __launch_bounds__(256) void news_kernel(
    const float* __restrict__ cand_sem,
    const float* __restrict__ nsem,
    const int* __restrict__ candidate_news_id,
    const int* __restrict__ neighbor_news,
    const int* __restrict__ neighbor_news_mask,
    const float* __restrict__ news_emb,
    const float* __restrict__ nid_W1, const float* __restrict__ nid_b1,
    const float* __restrict__ nid_w2, const float* __restrict__ nid_b2,
    const float* __restrict__ nsem_W1, const float* __restrict__ nsem_b1,
    const float* __restrict__ nsem_w2, const float* __restrict__ nsem_b2,
    const float* __restrict__ proj_W, const float* __restrict__ proj_b,
    float* __restrict__ out)
{
    const int b = blockIdx.x;
    const int tid = threadIdx.x, wid = tid >> 6, lane = tid & 63;
    __shared__ float li[NN_], ls[NN_];
    __shared__ float cat[896];

    for (int n0 = wid; n0 < NN_; n0 += 4) {
        if (neighbor_news_mask[b*NN_ + n0] != 0) {
            {
                const float* x = news_emb + (size_t)neighbor_news[b*NN_ + n0] * 128;
                float a0 = nid_b1[lane], a1 = nid_b1[lane + 64];
                for (int d = 0; d < 128; ++d) {
                    float xv = x[d];
                    a0 += xv * nid_W1[d*HID_ + lane];
                    a1 += xv * nid_W1[d*HID_ + lane + 64];
                }
                float v = tanhf(a0)*nid_w2[lane] + tanhf(a1)*nid_w2[lane + 64];
                #pragma unroll
                for (int off = 32; off > 0; off >>= 1) v += __shfl_down(v, off);
                if (lane == 0) li[n0] = v + nid_b2[0];
            }
            {
                const float* x = nsem + ((size_t)b*NN_ + n0) * SEM_;
                float a0 = nsem_b1[lane], a1 = nsem_b1[lane + 64];
                for (int d = 0; d < SEM_; ++d) {
                    float xv = x[d];
                    a0 += xv * nsem_W1[d*HID_ + lane];
                    a1 += xv * nsem_W1[d*HID_ + lane + 64];
                }
                float v = tanhf(a0)*nsem_w2[lane] + tanhf(a1)*nsem_w2[lane + 64];
                #pragma unroll
                for (int off = 32; off > 0; off >>= 1) v += __shfl_down(v, off);
                if (lane == 0) ls[n0] = v + nsem_b2[0];
            }
        } else if (lane == 0) { li[n0] = -1e30f; ls[n0] = -1e30f; }
    }
    __syncthreads();
    if (tid == 0) softmax_ip(li, NN_);
    else if (tid == 64) softmax_ip(ls, NN_);
    __syncthreads();

    for (int d = tid; d < SEM_; d += 256) cat[d] = cand_sem[(size_t)b*SEM_ + d];
    if (tid < 128) {
        cat[320 + tid] = news_emb[(size_t)candidate_news_id[b]*128 + tid];
        float acc = 0.f;
        for (int n = 0; n < NN_; ++n) acc += li[n] * news_emb[(size_t)neighbor_news[b*NN_ + n]*128 + tid];
        cat[448 + tid] = acc;
    }
    for (int d = tid; d < SEM_; d += 256) {
        float acc = 0.f;
        for (int n = 0; n < NN_; ++n) acc += ls[n] * nsem[((size_t)b*NN_ + n)*SEM_ + d];
        cat[576 + d] = acc;
    }
    __syncthreads();
    for (int j = tid; j < 576; j += 256) {
        float acc = proj_b[j];
        for (int d = 0; d < 896; ++d) acc += cat[d] * proj_W[(size_t)d*576 + j];
        out[(size_t)b*576 + j] = acc;
    }
}

extern "C" void kernel_launch(void* const* d_in, const int* in_sizes, int n_in,
                              void* d_out, int out_size, void* d_ws, size_t ws_size,
                              hipStream_t stream)
{
    const int* user_id            = (const int*)d_in[0];
    const int* candidate_news_id  = (const int*)d_in[1];
    const int* candidate_title    = (const int*)d_in[2];
    const int* candidate_topic    = (const int*)d_in[3];
    const int* clicked_title      = (const int*)d_in[4];
    const int* clicked_topic      = (const int*)d_in[5];
    const int* clicked_mask       = (const int*)d_in[6];
    const int* neighbor_users     = (const int*)d_in[7];
    const int* neighbor_user_mask = (const int*)d_in[8];
    const int* neighbor_news      = (const int*)d_in[9];
    const int* neighbor_news_mask = (const int*)d_in[10];
    const int* neighbor_title     = (const int*)d_in[11];
    const int* neighbor_topic     = (const int*)d_in[12];
    const float* user_emb  = (const float*)d_in[13];
    const float* news_emb  = (const float*)d_in[14];
    const float* word_emb  = (const float*)d_in[15];
    const float* topic_emb = (const float*)d_in[16];
    const float* Wq  = (const float*)d_in[17];
    const float* Wk  = (const float*)d_in[18];
    const float* Wv  = (const float*)d_in[19];
    const float* aW1 = (const float*)d_in[20];
    const float* ab1 = (const float*)d_in[21];
    const float* aw2 = (const float*)d_in[22];
    const float* clk_W1 = (const float*)d_in[23];
    const float* clk_b1 = (const float*)d_in[24];
    const float* clk_w2 = (const float*)d_in[25];
    const float* clk_b2 = (const float*)d_in[26];
    const float* uagg_W1 = (const float*)d_in[27];
    const float* uagg_b1 = (const float*)d_in[28];
    const float* uagg_w2 = (const float*)d_in[29];
    const float* uagg_b2 = (const float*)d_in[30];
    const float* nid_W1 = (const float*)d_in[31];
    const float* nid_b1 = (const float*)d_in[32];
    const float* nid_w2 = (const float*)d_in[33];
    const float* nid_b2 = (const float*)d_in[34];
    const float* nsem_W1 = (const float*)d_in[35];
    const float* nsem_b1 = (const float*)d_in[36];
    const float* nsem_w2 = (const float*)d_in[37];
    const float* nsem_b2 = (const float*)d_in[38];
    const float* proj_W = (const float*)d_in[39];
    const float* proj_b = (const float*)d_in[40];

    float* tf_out   = (float*)d_ws;                       // 8448 * 320 floats
    float* clk_sem  = tf_out;                             // [6400,320]
    float* cand_sem = tf_out + (size_t)B_*C_*SEM_;        // [128,320]
    float* nsem_buf = cand_sem + (size_t)B_*SEM_;         // [1920,320]

    tf_kernel<<<NSEQ_, 256, 0, stream>>>(clicked_title, clicked_topic,
        candidate_title, candidate_topic, neighbor_title, neighbor_topic,
        word_emb, topic_emb, Wq, Wk, Wv, aW1, ab1, aw2, tf_out);

    user_kernel<<<B_, 256, 0, stream>>>(clk_sem, clicked_mask, user_id,
        neighbor_users, neighbor_user_mask, user_emb,
        clk_W1, clk_b1, clk_w2, clk_b2, uagg_W1, uagg_b1, uagg_w2, uagg_b2,
        (float*)d_out);

    news_kernel<<<B_, 256, 0, stream>>>(cand_sem, nsem_buf,
        candidate_news_id, neighbor_news, neighbor_news_mask, news_emb,
        nid_W1, nid_b1, nid_w2, nid_b2, nsem_W1, nsem_b1, nsem_w2, nsem_b2,
        proj_W, proj_b, (float*)d_out + (size_t)B_*576);
}

// Round 2
// 1055.622 us; speedup vs baseline: 8.3384x; 8.3384x over previous
//
#include <hip/hip_runtime.h>
#include <hip/hip_bf16.h>
#include <math.h>

#define T_ 30
#define D_ 256
#define H_ 8
#define DH_ 32
#define HID_ 128
#define TD_ 64
#define SEM_ 320
#define B_ 128
#define C_ 50
#define NN_ 15
#define NU_ 15
#define NSEQ_ (B_*C_ + B_ + B_*NN_)   /* 8448 */

typedef short bf16x8 __attribute__((ext_vector_type(8)));
typedef float f32x4 __attribute__((ext_vector_type(4)));
#define MFMA16(a,b,c) __builtin_amdgcn_mfma_f32_16x16x32_bf16(a,b,c,0,0,0)

__device__ __forceinline__ unsigned short f2bf(float f) {
    union { float f; unsigned u; } v; v.f = f;
    unsigned u = v.u;
    u += 0x7FFFu + ((u >> 16) & 1u);      // RTNE
    return (unsigned short)(u >> 16);
}
__device__ __forceinline__ float bf2f(unsigned short s) {
    union { unsigned u; float f; } v; v.u = ((unsigned)s) << 16; return v.f;
}
__device__ __forceinline__ bf16x8 pack8(const float* p) {
    const float4 a = *(const float4*)p;
    const float4 b = *(const float4*)(p + 4);
    bf16x8 r;
    r[0]=(short)f2bf(a.x); r[1]=(short)f2bf(a.y); r[2]=(short)f2bf(a.z); r[3]=(short)f2bf(a.w);
    r[4]=(short)f2bf(b.x); r[5]=(short)f2bf(b.y); r[6]=(short)f2bf(b.z); r[7]=(short)f2bf(b.w);
    return r;
}

__device__ __forceinline__ void softmax_ip(float* v, int n) {
    float m = -1e30f;
    for (int i = 0; i < n; ++i) m = fmaxf(m, v[i]);
    float s = 0.f;
    for (int i = 0; i < n; ++i) { float e = __expf(v[i] - m); v[i] = e; s += e; }
    float inv = 1.f / s;
    for (int i = 0; i < n; ++i) v[i] *= inv;
}

// ---------------------------------------------------------------------------
// Prep: WT[768][256] = bf16([Wq|Wk|Wv] columns as rows); aW1T[128][256]
// ---------------------------------------------------------------------------
__global__ __launch_bounds__(256) void prep_kernel(
    const float* __restrict__ Wq, const float* __restrict__ Wk,
    const float* __restrict__ Wv, const float* __restrict__ aW1,
    unsigned short* __restrict__ WT, unsigned short* __restrict__ aW1T)
{
    int idx = blockIdx.x * 256 + threadIdx.x;
    if (idx < 768 * 256) {
        int n = idx >> 8, k = idx & 255;
        float v;
        if (n < 256)      v = Wq[k * 256 + n];
        else if (n < 512) v = Wk[k * 256 + (n - 256)];
        else              v = Wv[k * 256 + (n - 512)];
        WT[idx] = f2bf(v);
    } else if (idx < 768 * 256 + 128 * 256) {
        int j = idx - 768 * 256;
        int n = j >> 8, k = j & 255;
        aW1T[j] = f2bf(aW1[k * 128 + n]);
    }
}

// ---------------------------------------------------------------------------
// Transformer: one block (4 waves) per sequence, MFMA throughout.
// ---------------------------------------------------------------------------
__global__ __launch_bounds__(256) void tf_kernel(
    const int* __restrict__ clicked_title, const int* __restrict__ clicked_topic,
    const int* __restrict__ candidate_title, const int* __restrict__ candidate_topic,
    const int* __restrict__ neighbor_title, const int* __restrict__ neighbor_topic,
    const float* __restrict__ word_emb, const float* __restrict__ topic_emb,
    const unsigned short* __restrict__ WT, const unsigned short* __restrict__ aW1T,
    const float* __restrict__ ab1, const float* __restrict__ aw2,
    float* __restrict__ out)
{
    __shared__ __align__(16) unsigned short q_lds[32][264];   // 16896 B (stride 528B: 2-way = free)
    __shared__ __align__(16) unsigned short k_lds[32][264];
    __shared__ __align__(16) unsigned short o_lds[32][264];
    __shared__ __align__(16) unsigned short vt_lds[256][40];  // V^T: [dcol][token], 20480 B
    __shared__ __align__(16) unsigned short p_lds[4][32][32]; // per-wave P, 8192 B
    __shared__ float pls_part[4][32];
    __shared__ float pas_s[32];
    __shared__ int   toks[32];

    const int tid = threadIdx.x;
    const int l = tid & 63, w = tid >> 6;
    const int lm = l & 15, lg = l >> 4;        // lane-in-16, group 0..3
    const int rbase = lg * 4;
    const int i = blockIdx.x;

    const int* tok; int topic;
    if (i < B_*C_)            { tok = clicked_title   + i*T_;               topic = clicked_topic[i]; }
    else if (i < B_*C_ + B_)  { int j = i - B_*C_;      tok = candidate_title + j*T_; topic = candidate_topic[j]; }
    else                      { int j = i - (B_*C_+B_); tok = neighbor_title  + j*T_; topic = neighbor_topic[j]; }

    if (tid < 32) toks[tid] = (tid < T_) ? tok[tid] : 0;
    __syncthreads();

    // ---- A-fragments of x: afrag[mt][kt], rows 30/31 zero ----
    bf16x8 afrag[2][8];
    #pragma unroll
    for (int mt = 0; mt < 2; ++mt) {
        int row = mt * 16 + lm;
        if (row < T_) {
            const float* xr = word_emb + (size_t)toks[row] * D_;
            #pragma unroll
            for (int kt = 0; kt < 8; ++kt)
                afrag[mt][kt] = pack8(xr + kt * 32 + lg * 8);
        } else {
            #pragma unroll
            for (int kt = 0; kt < 8; ++kt) {
                bf16x8 z; 
                #pragma unroll
                for (int e = 0; e < 8; ++e) z[e] = 0;
                afrag[mt][kt] = z;
            }
        }
    }

    // ---- QKV GEMM: each wave 12 N-tiles of [Wq|Wk|Wv] (768 cols) ----
    for (int t = 0; t < 12; ++t) {
        const int n0 = (w * 12 + t) * 16;
        const unsigned short* wp = WT + (size_t)(n0 + lm) * 256 + lg * 8;
        f32x4 acc0 = {0.f,0.f,0.f,0.f}, acc1 = {0.f,0.f,0.f,0.f};
        #pragma unroll
        for (int kt = 0; kt < 8; ++kt) {
            bf16x8 b = *(const bf16x8*)(wp + kt * 32);
            acc0 = MFMA16(afrag[0][kt], b, acc0);
            acc1 = MFMA16(afrag[1][kt], b, acc1);
        }
        const int col = n0 + lm;
        const int which = col >> 8, lc = col & 255;
        if (which == 0) {
            #pragma unroll
            for (int r = 0; r < 4; ++r) {
                q_lds[rbase + r][lc]      = f2bf(acc0[r]);
                q_lds[16 + rbase + r][lc] = f2bf(acc1[r]);
            }
        } else if (which == 1) {
            #pragma unroll
            for (int r = 0; r < 4; ++r) {
                k_lds[rbase + r][lc]      = f2bf(acc0[r]);
                k_lds[16 + rbase + r][lc] = f2bf(acc1[r]);
            }
        } else {
            unsigned lo0 = (unsigned)f2bf(acc0[0]) | ((unsigned)f2bf(acc0[1]) << 16);
            unsigned hi0 = (unsigned)f2bf(acc0[2]) | ((unsigned)f2bf(acc0[3]) << 16);
            unsigned lo1 = (unsigned)f2bf(acc1[0]) | ((unsigned)f2bf(acc1[1]) << 16);
            unsigned hi1 = (unsigned)f2bf(acc1[2]) | ((unsigned)f2bf(acc1[3]) << 16);
            *(unsigned*)&vt_lds[lc][rbase]          = lo0;
            *(unsigned*)&vt_lds[lc][rbase + 2]      = hi0;
            *(unsigned*)&vt_lds[lc][16 + rbase]     = lo1;
            *(unsigned*)&vt_lds[lc][16 + rbase + 2] = hi1;
        }
    }
    __syncthreads();

    // ---- Attention: 2 heads per wave, K=32 = one fragment ----
    const float sc = 0.17677669529663687f;   // 1/sqrt(32)
    const int kb = lg * 8;
    for (int hh = 0; hh < 2; ++hh) {
        const int h = 2 * w + hh, cb = h * DH_;
        bf16x8 aq0 = *(const bf16x8*)&q_lds[lm][cb + kb];
        bf16x8 aq1 = *(const bf16x8*)&q_lds[16 + lm][cb + kb];
        bf16x8 bk0 = *(const bf16x8*)&k_lds[lm][cb + kb];
        bf16x8 bk1 = *(const bf16x8*)&k_lds[16 + lm][cb + kb];
        f32x4 z = {0.f,0.f,0.f,0.f};
        f32x4 s00 = MFMA16(aq0, bk0, z);   // rows 0-15, keys 0-15
        f32x4 s01 = MFMA16(aq0, bk1, z);   // rows 0-15, keys 16-31
        f32x4 s10 = MFMA16(aq1, bk0, z);
        f32x4 s11 = MFMA16(aq1, bk1, z);
        #pragma unroll
        for (int r = 0; r < 4; ++r) {
            s00[r] *= sc; s01[r] *= sc; s10[r] *= sc; s11[r] *= sc;
            if (lm >= 14) { s01[r] = -1e30f; s11[r] = -1e30f; }   // mask keys 30,31
        }
        // in-register softmax per row (reduce across 16-lane group)
        #pragma unroll
        for (int r = 0; r < 4; ++r) {
            float mx0 = fmaxf(s00[r], s01[r]);
            float mx1 = fmaxf(s10[r], s11[r]);
            #pragma unroll
            for (int d = 1; d < 16; d <<= 1) {
                mx0 = fmaxf(mx0, __shfl_xor(mx0, d));
                mx1 = fmaxf(mx1, __shfl_xor(mx1, d));
            }
            float e00 = __expf(s00[r] - mx0), e01 = __expf(s01[r] - mx0);
            float e10 = __expf(s10[r] - mx1), e11 = __expf(s11[r] - mx1);
            float sm0 = e00 + e01, sm1 = e10 + e11;
            #pragma unroll
            for (int d = 1; d < 16; d <<= 1) {
                sm0 += __shfl_xor(sm0, d);
                sm1 += __shfl_xor(sm1, d);
            }
            float inv0 = 1.f / sm0, inv1 = 1.f / sm1;
            p_lds[w][rbase + r][lm]           = f2bf(e00 * inv0);
            p_lds[w][rbase + r][16 + lm]      = f2bf(e01 * inv0);
            p_lds[w][16 + rbase + r][lm]      = f2bf(e10 * inv1);
            p_lds[w][16 + rbase + r][16 + lm] = f2bf(e11 * inv1);
        }
        // PV: O[q][d] = P @ V   (B-frag = contiguous row of V^T)
        bf16x8 ap0 = *(const bf16x8*)&p_lds[w][lm][kb];
        bf16x8 ap1 = *(const bf16x8*)&p_lds[w][16 + lm][kb];
        bf16x8 bv0 = *(const bf16x8*)&vt_lds[cb + lm][kb];
        bf16x8 bv1 = *(const bf16x8*)&vt_lds[cb + 16 + lm][kb];
        f32x4 o00 = MFMA16(ap0, bv0, z);
        f32x4 o01 = MFMA16(ap0, bv1, z);
        f32x4 o10 = MFMA16(ap1, bv0, z);
        f32x4 o11 = MFMA16(ap1, bv1, z);
        #pragma unroll
        for (int r = 0; r < 4; ++r) {
            o_lds[rbase + r][cb + lm]           = f2bf(o00[r]);
            o_lds[rbase + r][cb + 16 + lm]      = f2bf(o01[r]);
            o_lds[16 + rbase + r][cb + lm]      = f2bf(o10[r]);
            o_lds[16 + rbase + r][cb + 16 + lm] = f2bf(o11[r]);
        }
    }
    __syncthreads();

    // ---- Pooling GEMM: hidden = o @ aW1T^T, per wave 32 hidden cols ----
    f32x4 h00 = {0.f,0.f,0.f,0.f}, h01 = h00, h10 = h00, h11 = h00;
    {
        const unsigned short* w0p = aW1T + (size_t)(w * 32 + lm) * 256 + kb;
        const unsigned short* w1p = aW1T + (size_t)(w * 32 + 16 + lm) * 256 + kb;
        #pragma unroll
        for (int kt = 0; kt < 8; ++kt) {
            bf16x8 ao0 = *(const bf16x8*)&o_lds[lm][kt * 32 + kb];
            bf16x8 ao1 = *(const bf16x8*)&o_lds[16 + lm][kt * 32 + kb];
            bf16x8 bw0 = *(const bf16x8*)(w0p + kt * 32);
            bf16x8 bw1 = *(const bf16x8*)(w1p + kt * 32);
            h00 = MFMA16(ao0, bw0, h00);
            h01 = MFMA16(ao0, bw1, h01);
            h10 = MFMA16(ao1, bw0, h10);
            h11 = MFMA16(ao1, bw1, h11);
        }
    }
    {
        const int c0 = w * 32 + lm, c1 = c0 + 16;
        const float b0 = ab1[c0], b1 = ab1[c1];
        const float a20 = aw2[c0], a21 = aw2[c1];
        #pragma unroll
        for (int r = 0; r < 4; ++r) {
            float v0 = tanhf(h00[r] + b0) * a20 + tanhf(h01[r] + b1) * a21;
            float v1 = tanhf(h10[r] + b0) * a20 + tanhf(h11[r] + b1) * a21;
            #pragma unroll
            for (int d = 1; d < 16; d <<= 1) {
                v0 += __shfl_xor(v0, d);
                v1 += __shfl_xor(v1, d);
            }
            if (lm == 0) {
                pls_part[w][rbase + r]      = v0;
                pls_part[w][16 + rbase + r] = v1;
            }
        }
    }
    __syncthreads();
    if (tid == 0) {
        float pl[T_];
        float m = -1e30f;
        for (int r = 0; r < T_; ++r) {
            pl[r] = pls_part[0][r] + pls_part[1][r] + pls_part[2][r] + pls_part[3][r];
            m = fmaxf(m, pl[r]);
        }
        float sum = 0.f;
        for (int r = 0; r < T_; ++r) { float e = __expf(pl[r] - m); pl[r] = e; sum += e; }
        float inv = 1.f / sum;
        for (int r = 0; r < T_; ++r) pas_s[r] = pl[r] * inv;
        pas_s[30] = 0.f; pas_s[31] = 0.f;
    }
    __syncthreads();

    // ---- title = pa @ o ; concat topic ----
    {
        float acc = 0.f;
        for (int r = 0; r < T_; ++r) acc += pas_s[r] * bf2f(o_lds[r][tid]);
        out[(size_t)i * SEM_ + tid] = acc;
    }
    if (tid < TD_) out[(size_t)i * SEM_ + D_ + tid] = topic_emb[(size_t)topic * TD_ + tid];
}

// ---------------------------------------------------------------------------
// User branch (unchanged from R1)
// ---------------------------------------------------------------------------
__global__ __launch_bounds__(256) void user_kernel(
    const float* __restrict__ clk_sem,
    const int* __restrict__ clicked_mask,
    const int* __restrict__ user_id,
    const int* __restrict__ neighbor_users,
    const int* __restrict__ neighbor_user_mask,
    const float* __restrict__ user_emb,
    const float* __restrict__ clk_W1, const float* __restrict__ clk_b1,
    const float* __restrict__ clk_w2, const float* __restrict__ clk_b2,
    const float* __restrict__ uagg_W1, const float* __restrict__ uagg_b1,
    const float* __restrict__ uagg_w2, const float* __restrict__ uagg_b2,
    float* __restrict__ out)
{
    const int b = blockIdx.x;
    const int tid = threadIdx.x, wid = tid >> 6, lane = tid & 63;
    __shared__ float lc[C_], lu[NU_];

    for (int c0 = wid; c0 < C_; c0 += 4) {
        if (clicked_mask[b*C_ + c0] != 0) {
            const float* x = clk_sem + ((size_t)b*C_ + c0) * SEM_;
            float a0 = clk_b1[lane], a1 = clk_b1[lane + 64];
            for (int d = 0; d < SEM_; ++d) {
                float xv = x[d];
                a0 += xv * clk_W1[d*HID_ + lane];
                a1 += xv * clk_W1[d*HID_ + lane + 64];
            }
            float v = tanhf(a0)*clk_w2[lane] + tanhf(a1)*clk_w2[lane + 64];
            #pragma unroll
            for (int off = 32; off > 0; off >>= 1) v += __shfl_down(v, off);
            if (lane == 0) lc[c0] = v + clk_b2[0];
        } else if (lane == 0) lc[c0] = -1e30f;
    }
    for (int n0 = wid; n0 < NU_; n0 += 4) {
        if (neighbor_user_mask[b*NU_ + n0] != 0) {
            const float* x = user_emb + (size_t)neighbor_users[b*NU_ + n0] * 128;
            float a0 = uagg_b1[lane], a1 = uagg_b1[lane + 64];
            for (int d = 0; d < 128; ++d) {
                float xv = x[d];
                a0 += xv * uagg_W1[d*HID_ + lane];
                a1 += xv * uagg_W1[d*HID_ + lane + 64];
            }
            float v = tanhf(a0)*uagg_w2[lane] + tanhf(a1)*uagg_w2[lane + 64];
            #pragma unroll
            for (int off = 32; off > 0; off >>= 1) v += __shfl_down(v, off);
            if (lane == 0) lu[n0] = v + uagg_b2[0];
        } else if (lane == 0) lu[n0] = -1e30f;
    }
    __syncthreads();
    if (tid == 0) softmax_ip(lc, C_);
    else if (tid == 64) softmax_ip(lu, NU_);
    __syncthreads();

    for (int d = tid; d < SEM_; d += 256) {
        float acc = 0.f;
        for (int c = 0; c < C_; ++c) acc += lc[c] * clk_sem[((size_t)b*C_ + c)*SEM_ + d];
        out[(size_t)b*576 + d] = acc;
    }
    if (tid < 128) {
        out[(size_t)b*576 + 320 + tid] = user_emb[(size_t)user_id[b]*128 + tid];
        float acc = 0.f;
        for (int n = 0; n < NU_; ++n) acc += lu[n] * user_emb[(size_t)neighbor_users[b*NU_ + n]*128 + tid];
        out[(size_t)b*576 + 448 + tid] = acc;
    }
}

// ---------------------------------------------------------------------------
// News branch (unchanged from R1)
// ---------------------------------------------------------------------------
__global__ __launch_bounds__(256) void news_kernel(
    const float* __restrict__ cand_sem,
    const float* __restrict__ nsem,
    const int* __restrict__ candidate_news_id,
    const int* __restrict__ neighbor_news,
    const int* __restrict__ neighbor_news_mask,
    const float* __restrict__ news_emb,
    const float* __restrict__ nid_W1, const float* __restrict__ nid_b1,
    const float* __restrict__ nid_w2, const float* __restrict__ nid_b2,
    const float* __restrict__ nsem_W1, const float* __restrict__ nsem_b1,
    const float* __restrict__ nsem_w2, const float* __restrict__ nsem_b2,
    const float* __restrict__ proj_W, const float* __restrict__ proj_b,
    float* __restrict__ out)
{
    const int b = blockIdx.x;
    const int tid = threadIdx.x, wid = tid >> 6, lane = tid & 63;
    __shared__ float li[NN_], ls[NN_];
    __shared__ float cat[896];

    for (int n0 = wid; n0 < NN_; n0 += 4) {
        if (neighbor_news_mask[b*NN_ + n0] != 0) {
            {
                const float* x = news_emb + (size_t)neighbor_news[b*NN_ + n0] * 128;
                float a0 = nid_b1[lane], a1 = nid_b1[lane + 64];
                for (int d = 0; d < 128; ++d) {
                    float xv = x[d];
                    a0 += xv * nid_W1[d*HID_ + lane];
                    a1 += xv * nid_W1[d*HID_ + lane + 64];
                }
                float v = tanhf(a0)*nid_w2[lane] + tanhf(a1)*nid_w2[lane + 64];
                #pragma unroll
                for (int off = 32; off > 0; off >>= 1) v += __shfl_down(v, off);
                if (lane == 0) li[n0] = v + nid_b2[0];
            }
            {
                const float* x = nsem + ((size_t)b*NN_ + n0) * SEM_;
                float a0 = nsem_b1[lane], a1 = nsem_b1[lane + 64];
                for (int d = 0; d < SEM_; ++d) {
                    float xv = x[d];
                    a0 += xv * nsem_W1[d*HID_ + lane];
                    a1 += xv * nsem_W1[d*HID_ + lane + 64];
                }
                float v = tanhf(a0)*nsem_w2[lane] + tanhf(a1)*nsem_w2[lane + 64];
                #pragma unroll
                for (int off = 32; off > 0; off >>= 1) v += __shfl_down(v, off);
                if (lane == 0) ls[n0] = v + nsem_b2[0];
            }
        } else if (lane == 0) { li[n0] = -1e30f; ls[n0] = -1e30f; }
    }
    __syncthreads();
    if (tid == 0) softmax_ip(li, NN_);
    else if (tid == 64) softmax_ip(ls, NN_);
    __syncthreads();

    for (int d = tid; d < SEM_; d += 256) cat[d] = cand_sem[(size_t)b*SEM_ + d];
    if (tid < 128) {
        cat[320 + tid] = news_emb[(size_t)candidate_news_id[b]*128 + tid];
        float acc = 0.f;
        for (int n = 0; n < NN_; ++n) acc += li[n] * news_emb[(size_t)neighbor_news[b*NN_ + n]*128 + tid];
        cat[448 + tid] = acc;
    }
    for (int d = tid; d < SEM_; d += 256) {
        float acc = 0.f;
        for (int n = 0; n < NN_; ++n) acc += ls[n] * nsem[((size_t)b*NN_ + n)*SEM_ + d];
        cat[576 + d] = acc;
    }
    __syncthreads();
    for (int j = tid; j < 576; j += 256) {
        float acc = proj_b[j];
        for (int d = 0; d < 896; ++d) acc += cat[d] * proj_W[(size_t)d*576 + j];
        out[(size_t)b*576 + j] = acc;
    }
}

extern "C" void kernel_launch(void* const* d_in, const int* in_sizes, int n_in,
                              void* d_out, int out_size, void* d_ws, size_t ws_size,
                              hipStream_t stream)
{
    const int* user_id            = (const int*)d_in[0];
    const int* candidate_news_id  = (const int*)d_in[1];
    const int* candidate_title    = (const int*)d_in[2];
    const int* candidate_topic    = (const int*)d_in[3];
    const int* clicked_title      = (const int*)d_in[4];
    const int* clicked_topic      = (const int*)d_in[5];
    const int* clicked_mask       = (const int*)d_in[6];
    const int* neighbor_users     = (const int*)d_in[7];
    const int* neighbor_user_mask = (const int*)d_in[8];
    const int* neighbor_news      = (const int*)d_in[9];
    const int* neighbor_news_mask = (const int*)d_in[10];
    const int* neighbor_title     = (const int*)d_in[11];
    const int* neighbor_topic     = (const int*)d_in[12];
    const float* user_emb  = (const float*)d_in[13];
    const float* news_emb  = (const float*)d_in[14];
    const float* word_emb  = (const float*)d_in[15];
    const float* topic_emb = (const float*)d_in[16];
    const float* Wq  = (const float*)d_in[17];
    const float* Wk  = (const float*)d_in[18];
    const float* Wv  = (const float*)d_in[19];
    const float* aW1 = (const float*)d_in[20];
    const float* ab1 = (const float*)d_in[21];
    const float* aw2 = (const float*)d_in[22];
    const float* clk_W1 = (const float*)d_in[23];
    const float* clk_b1 = (const float*)d_in[24];
    const float* clk_w2 = (const float*)d_in[25];
    const float* clk_b2 = (const float*)d_in[26];
    const float* uagg_W1 = (const float*)d_in[27];
    const float* uagg_b1 = (const float*)d_in[28];
    const float* uagg_w2 = (const float*)d_in[29];
    const float* uagg_b2 = (const float*)d_in[30];
    const float* nid_W1 = (const float*)d_in[31];
    const float* nid_b1 = (const float*)d_in[32];
    const float* nid_w2 = (const float*)d_in[33];
    const float* nid_b2 = (const float*)d_in[34];
    const float* nsem_W1 = (const float*)d_in[35];
    const float* nsem_b1 = (const float*)d_in[36];
    const float* nsem_w2 = (const float*)d_in[37];
    const float* nsem_b2 = (const float*)d_in[38];
    const float* proj_W = (const float*)d_in[39];
    const float* proj_b = (const float*)d_in[40];

    // workspace layout
    float* tf_out = (float*)d_ws;                                   // 8448*320 f32 = 10813440 B
    unsigned short* WT   = (unsigned short*)((char*)d_ws + (size_t)NSEQ_ * SEM_ * 4);  // 768*256*2
    unsigned short* aW1T = WT + 768 * 256;                          // 128*256*2
    float* clk_sem  = tf_out;
    float* cand_sem = tf_out + (size_t)B_*C_*SEM_;
    float* nsem_buf = cand_sem + (size_t)B_*SEM_;

    prep_kernel<<<(768*256 + 128*256 + 255) / 256, 256, 0, stream>>>(
        Wq, Wk, Wv, aW1, WT, aW1T);

    tf_kernel<<<NSEQ_, 256, 0, stream>>>(clicked_title, clicked_topic,
        candidate_title, candidate_topic, neighbor_title, neighbor_topic,
        word_emb, topic_emb, WT, aW1T, ab1, aw2, tf_out);

    user_kernel<<<B_, 256, 0, stream>>>(clk_sem, clicked_mask, user_id,
        neighbor_users, neighbor_user_mask, user_emb,
        clk_W1, clk_b1, clk_w2, clk_b2, uagg_W1, uagg_b1, uagg_w2, uagg_b2,
        (float*)d_out);

    news_kernel<<<B_, 256, 0, stream>>>(cand_sem, nsem_buf,
        candidate_news_id, neighbor_news, neighbor_news_mask, news_emb,
        nid_W1, nid_b1, nid_w2, nid_b2, nsem_W1, nsem_b1, nsem_w2, nsem_b2,
        proj_W, proj_b, (float*)d_out + (size_t)B_*576);
}

// Round 3
// 876.577 us; speedup vs baseline: 10.0415x; 1.2043x over previous
//
#include <hip/hip_runtime.h>
#include <hip/hip_bf16.h>
#include <math.h>

#define T_ 30
#define D_ 256
#define H_ 8
#define DH_ 32
#define HID_ 128
#define TD_ 64
#define SEM_ 320
#define B_ 128
#define C_ 50
#define NN_ 15
#define NU_ 15
#define NSEQ_ (B_*C_ + B_ + B_*NN_)   /* 8448 */

typedef short bf16x8 __attribute__((ext_vector_type(8)));
typedef float f32x4 __attribute__((ext_vector_type(4)));
#define MFMA16(a,b,c) __builtin_amdgcn_mfma_f32_16x16x32_bf16(a,b,c,0,0,0)

typedef unsigned short ushort_t;

__device__ __forceinline__ unsigned short f2bf(float f) {
    union { float f; unsigned u; } v; v.f = f;
    unsigned u = v.u;
    u += 0x7FFFu + ((u >> 16) & 1u);      // RTNE
    return (unsigned short)(u >> 16);
}
__device__ __forceinline__ float bf2f(unsigned short s) {
    union { unsigned u; float f; } v; v.u = ((unsigned)s) << 16; return v.f;
}
__device__ __forceinline__ bf16x8 pack8(const float* p) {
    const float4 a = *(const float4*)p;
    const float4 b = *(const float4*)(p + 4);
    bf16x8 r;
    r[0]=(short)f2bf(a.x); r[1]=(short)f2bf(a.y); r[2]=(short)f2bf(a.z); r[3]=(short)f2bf(a.w);
    r[4]=(short)f2bf(b.x); r[5]=(short)f2bf(b.y); r[6]=(short)f2bf(b.z); r[7]=(short)f2bf(b.w);
    return r;
}

// ---------------------------------------------------------------------------
// Prep: transpose+bf16 all weight matrices.
//   WT[768][256] <- [Wq|Wk|Wv] ; aW1T[128][256] ; WtClk[128][320] ;
//   WtU[128][128] ; WtNid[128][128] ; WtNsem[128][320] ; projT[576][896]
// ---------------------------------------------------------------------------
#define PREP_TOTAL (196608 + 32768 + 40960 + 16384 + 16384 + 40960 + 516096)
__global__ __launch_bounds__(256) void prep_kernel(
    const float* __restrict__ Wq, const float* __restrict__ Wk,
    const float* __restrict__ Wv, const float* __restrict__ aW1,
    const float* __restrict__ clk_W1, const float* __restrict__ uagg_W1,
    const float* __restrict__ nid_W1, const float* __restrict__ nsem_W1,
    const float* __restrict__ proj_W,
    unsigned short* __restrict__ WT, unsigned short* __restrict__ aW1T,
    unsigned short* __restrict__ WtClk, unsigned short* __restrict__ WtU,
    unsigned short* __restrict__ WtNid, unsigned short* __restrict__ WtNsem,
    unsigned short* __restrict__ projT)
{
    int idx = blockIdx.x * 256 + threadIdx.x;
    if (idx < 196608) {
        int n = idx >> 8, k = idx & 255;
        float v;
        if (n < 256)      v = Wq[k * 256 + n];
        else if (n < 512) v = Wk[k * 256 + (n - 256)];
        else              v = Wv[k * 256 + (n - 512)];
        WT[idx] = f2bf(v);
    } else if (idx < 196608 + 32768) {
        int j = idx - 196608; int n = j >> 8, k = j & 255;
        aW1T[j] = f2bf(aW1[k * 128 + n]);
    } else if (idx < 229376 + 40960) {
        int j = idx - 229376; int n = j / 320, k = j - n * 320;
        WtClk[j] = f2bf(clk_W1[k * 128 + n]);
    } else if (idx < 270336 + 16384) {
        int j = idx - 270336; int n = j >> 7, k = j & 127;
        WtU[j] = f2bf(uagg_W1[k * 128 + n]);
    } else if (idx < 286720 + 16384) {
        int j = idx - 286720; int n = j >> 7, k = j & 127;
        WtNid[j] = f2bf(nid_W1[k * 128 + n]);
    } else if (idx < 303104 + 40960) {
        int j = idx - 303104; int n = j / 320, k = j - n * 320;
        WtNsem[j] = f2bf(nsem_W1[k * 128 + n]);
    } else if (idx < PREP_TOTAL) {
        int j = idx - 344064; int n = j / 896, k = j - n * 896;
        projT[j] = f2bf(proj_W[(size_t)k * 576 + n]);
    }
}

// ---------------------------------------------------------------------------
// tf_core: one block (4 waves) per sequence. QKV + attention + pooling,
// writes sem bf16 [NSEQ][320]. LDS = 54272 B -> 3 blocks/CU.
// ---------------------------------------------------------------------------
__global__ __launch_bounds__(256, 3) void tf_core(
    const int* __restrict__ clicked_title, const int* __restrict__ clicked_topic,
    const int* __restrict__ candidate_title, const int* __restrict__ candidate_topic,
    const int* __restrict__ neighbor_title, const int* __restrict__ neighbor_topic,
    const float* __restrict__ word_emb, const float* __restrict__ topic_emb,
    const unsigned short* __restrict__ WT, const unsigned short* __restrict__ aW1T,
    const float* __restrict__ ab1, const float* __restrict__ aw2,
    unsigned short* __restrict__ sem)
{
    __shared__ __align__(16) unsigned short qo[32][264];   // Q, then O (aliased; per-wave col slices)
    __shared__ __align__(16) unsigned short kp[32][264];   // K, then per-wave P; tail reused for pls/pas
    __shared__ __align__(16) unsigned short vt[256][40];   // V^T [dcol][token]

    float* pls_part = (float*)(&kp[0][0]);                 // [4][32], written after K/P dead
    float* pas_s    = (float*)((char*)(&kp[0][0]) + 512);  // [32]

    const int tid = threadIdx.x;
    const int l = tid & 63, w = tid >> 6;
    const int lm = l & 15, lg = l >> 4;
    const int rbase = lg * 4;
    const int kb = lg * 8;
    const int i = blockIdx.x;

    const int* tok; int topic;
    if (i < B_*C_)            { tok = clicked_title   + i*T_;               topic = clicked_topic[i]; }
    else if (i < B_*C_ + B_)  { int j = i - B_*C_;      tok = candidate_title + j*T_; topic = candidate_topic[j]; }
    else                      { int j = i - (B_*C_+B_); tok = neighbor_title  + j*T_; topic = neighbor_topic[j]; }

    // ---- A-fragments of x (rows 30/31 zero) ----
    bf16x8 afrag[2][8];
    #pragma unroll
    for (int mt = 0; mt < 2; ++mt) {
        int row = mt * 16 + lm;
        if (row < T_) {
            const float* xr = word_emb + (size_t)tok[row] * D_;
            #pragma unroll
            for (int kt = 0; kt < 8; ++kt)
                afrag[mt][kt] = pack8(xr + kt * 32 + kb);
        } else {
            #pragma unroll
            for (int kt = 0; kt < 8; ++kt) {
                bf16x8 z;
                #pragma unroll
                for (int e = 0; e < 8; ++e) z[e] = 0;
                afrag[mt][kt] = z;
            }
        }
    }

    // ---- QKV GEMM: wave w handles N-tiles 12w..12w+11; half-tile double buffer ----
    {
        const unsigned short* wtb = WT + (size_t)lm * 256 + kb;
        bf16x8 bufA[4], bufB[4];
        f32x4 acc0, acc1;

        #define LOADH(buf, h_) { \
            const unsigned short* p_ = wtb + (size_t)((w * 12 + ((h_) >> 1)) * 16) * 256 + ((h_) & 1) * 128; \
            buf[0] = *(const bf16x8*)(p_);      buf[1] = *(const bf16x8*)(p_ + 32); \
            buf[2] = *(const bf16x8*)(p_ + 64); buf[3] = *(const bf16x8*)(p_ + 96); }
        #define CONSUME(buf, h_) { \
            const int kt0_ = ((h_) & 1) * 4; \
            acc0 = MFMA16(afrag[0][kt0_+0], buf[0], acc0); acc1 = MFMA16(afrag[1][kt0_+0], buf[0], acc1); \
            acc0 = MFMA16(afrag[0][kt0_+1], buf[1], acc0); acc1 = MFMA16(afrag[1][kt0_+1], buf[1], acc1); \
            acc0 = MFMA16(afrag[0][kt0_+2], buf[2], acc0); acc1 = MFMA16(afrag[1][kt0_+2], buf[2], acc1); \
            acc0 = MFMA16(afrag[0][kt0_+3], buf[3], acc0); acc1 = MFMA16(afrag[1][kt0_+3], buf[3], acc1); }

        LOADH(bufA, 0);
        #pragma unroll
        for (int t = 0; t < 12; ++t) {
            acc0 = (f32x4){0.f,0.f,0.f,0.f};
            acc1 = (f32x4){0.f,0.f,0.f,0.f};
            LOADH(bufB, 2*t + 1);
            CONSUME(bufA, 2*t);
            if (t < 11) LOADH(bufA, 2*t + 2);
            CONSUME(bufB, 2*t + 1);
            // store tile t
            {
                const int n0 = (w * 12 + t) * 16;
                const int which = n0 >> 8;
                const int lc = (n0 + lm) & 255;
                if (which == 0) {
                    #pragma unroll
                    for (int r = 0; r < 4; ++r) {
                        qo[rbase + r][lc]      = f2bf(acc0[r]);
                        qo[16 + rbase + r][lc] = f2bf(acc1[r]);
                    }
                } else if (which == 1) {
                    #pragma unroll
                    for (int r = 0; r < 4; ++r) {
                        kp[rbase + r][lc]      = f2bf(acc0[r]);
                        kp[16 + rbase + r][lc] = f2bf(acc1[r]);
                    }
                } else {
                    unsigned lo0 = (unsigned)f2bf(acc0[0]) | ((unsigned)f2bf(acc0[1]) << 16);
                    unsigned hi0 = (unsigned)f2bf(acc0[2]) | ((unsigned)f2bf(acc0[3]) << 16);
                    unsigned lo1 = (unsigned)f2bf(acc1[0]) | ((unsigned)f2bf(acc1[1]) << 16);
                    unsigned hi1 = (unsigned)f2bf(acc1[2]) | ((unsigned)f2bf(acc1[3]) << 16);
                    *(unsigned*)&vt[lc][rbase]          = lo0;
                    *(unsigned*)&vt[lc][rbase + 2]      = hi0;
                    *(unsigned*)&vt[lc][16 + rbase]     = lo1;
                    *(unsigned*)&vt[lc][16 + rbase + 2] = hi1;
                }
            }
        }
        #undef LOADH
        #undef CONSUME
    }
    __syncthreads();

    // ---- Attention: 2 heads/wave; P reuses dead K cols [64w..64w+31] ----
    const float sc = 0.17677669529663687f;   // 1/sqrt(32)
    const int pcb = w * 64;
    #pragma unroll
    for (int hh = 0; hh < 2; ++hh) {
        const int h = 2 * w + hh, cb = h * DH_;
        bf16x8 aq0 = *(const bf16x8*)&qo[lm][cb + kb];
        bf16x8 aq1 = *(const bf16x8*)&qo[16 + lm][cb + kb];
        bf16x8 bk0 = *(const bf16x8*)&kp[lm][cb + kb];
        bf16x8 bk1 = *(const bf16x8*)&kp[16 + lm][cb + kb];
        f32x4 z = {0.f,0.f,0.f,0.f};
        f32x4 s00 = MFMA16(aq0, bk0, z);
        f32x4 s01 = MFMA16(aq0, bk1, z);
        f32x4 s10 = MFMA16(aq1, bk0, z);
        f32x4 s11 = MFMA16(aq1, bk1, z);
        #pragma unroll
        for (int r = 0; r < 4; ++r) {
            s00[r] *= sc; s01[r] *= sc; s10[r] *= sc; s11[r] *= sc;
            if (lm >= 14) { s01[r] = -1e30f; s11[r] = -1e30f; }   // keys 30,31
        }
        #pragma unroll
        for (int r = 0; r < 4; ++r) {
            float mx0 = fmaxf(s00[r], s01[r]);
            float mx1 = fmaxf(s10[r], s11[r]);
            #pragma unroll
            for (int d = 1; d < 16; d <<= 1) {
                mx0 = fmaxf(mx0, __shfl_xor(mx0, d));
                mx1 = fmaxf(mx1, __shfl_xor(mx1, d));
            }
            float e00 = __expf(s00[r] - mx0), e01 = __expf(s01[r] - mx0);
            float e10 = __expf(s10[r] - mx1), e11 = __expf(s11[r] - mx1);
            float sm0 = e00 + e01, sm1 = e10 + e11;
            #pragma unroll
            for (int d = 1; d < 16; d <<= 1) {
                sm0 += __shfl_xor(sm0, d);
                sm1 += __shfl_xor(sm1, d);
            }
            float inv0 = 1.f / sm0, inv1 = 1.f / sm1;
            kp[rbase + r][pcb + lm]           = f2bf(e00 * inv0);
            kp[rbase + r][pcb + 16 + lm]      = f2bf(e01 * inv0);
            kp[16 + rbase + r][pcb + lm]      = f2bf(e10 * inv1);
            kp[16 + rbase + r][pcb + 16 + lm] = f2bf(e11 * inv1);
        }
        bf16x8 ap0 = *(const bf16x8*)&kp[lm][pcb + kb];
        bf16x8 ap1 = *(const bf16x8*)&kp[16 + lm][pcb + kb];
        bf16x8 bv0 = *(const bf16x8*)&vt[cb + lm][kb];
        bf16x8 bv1 = *(const bf16x8*)&vt[cb + 16 + lm][kb];
        f32x4 o00 = MFMA16(ap0, bv0, z);
        f32x4 o01 = MFMA16(ap0, bv1, z);
        f32x4 o10 = MFMA16(ap1, bv0, z);
        f32x4 o11 = MFMA16(ap1, bv1, z);
        #pragma unroll
        for (int r = 0; r < 4; ++r) {
            qo[rbase + r][cb + lm]           = f2bf(o00[r]);
            qo[rbase + r][cb + 16 + lm]      = f2bf(o01[r]);
            qo[16 + rbase + r][cb + lm]      = f2bf(o10[r]);
            qo[16 + rbase + r][cb + 16 + lm] = f2bf(o11[r]);
        }
    }
    __syncthreads();

    // ---- Pooling GEMM: hidden = o @ aW1; wave w -> hidden cols [32w..32w+31] ----
    {
        f32x4 h00 = {0.f,0.f,0.f,0.f}, h01 = h00, h10 = h00, h11 = h00;
        const unsigned short* w0p = aW1T + (size_t)(w * 32 + lm) * 256 + kb;
        const unsigned short* w1p = aW1T + (size_t)(w * 32 + 16 + lm) * 256 + kb;
        #pragma unroll
        for (int kt = 0; kt < 8; ++kt) {
            bf16x8 ao0 = *(const bf16x8*)&qo[lm][kt * 32 + kb];
            bf16x8 ao1 = *(const bf16x8*)&qo[16 + lm][kt * 32 + kb];
            bf16x8 bw0 = *(const bf16x8*)(w0p + kt * 32);
            bf16x8 bw1 = *(const bf16x8*)(w1p + kt * 32);
            h00 = MFMA16(ao0, bw0, h00);
            h01 = MFMA16(ao0, bw1, h01);
            h10 = MFMA16(ao1, bw0, h10);
            h11 = MFMA16(ao1, bw1, h11);
        }
        const int c0 = w * 32 + lm, c1 = c0 + 16;
        const float b0 = ab1[c0], b1 = ab1[c1];
        const float a20 = aw2[c0], a21 = aw2[c1];
        float vsum[4];
        #pragma unroll
        for (int r = 0; r < 4; ++r) {
            float v0 = tanhf(h00[r] + b0) * a20 + tanhf(h01[r] + b1) * a21;
            float v1 = tanhf(h10[r] + b0) * a20 + tanhf(h11[r] + b1) * a21;
            #pragma unroll
            for (int d = 1; d < 16; d <<= 1) {
                v0 += __shfl_xor(v0, d);
                v1 += __shfl_xor(v1, d);
            }
            vsum[r] = v0;
            if (lm == 0) pls_part[w * 32 + 16 + rbase + r] = v1;
            (void)vsum;
        }
        #pragma unroll
        for (int r = 0; r < 4; ++r)
            if (lm == 0) pls_part[w * 32 + rbase + r] = __shfl(vsum[r], lg * 16);
    }
    __syncthreads();

    // ---- final softmax over 30 (wave 0, parallel) ----
    if (w == 0) {
        float pl = -1e30f;
        if (l < T_) pl = pls_part[l] + pls_part[32 + l] + pls_part[64 + l] + pls_part[96 + l];
        float m = pl;
        #pragma unroll
        for (int d = 1; d < 64; d <<= 1) m = fmaxf(m, __shfl_xor(m, d));
        float e = (l < T_) ? __expf(pl - m) : 0.f;
        float s = e;
        #pragma unroll
        for (int d = 1; d < 64; d <<= 1) s += __shfl_xor(s, d);
        if (l < 32) pas_s[l] = e / s;
    }
    __syncthreads();

    // ---- title = pa @ o (bf16 out); concat topic ----
    {
        float acc = 0.f;
        #pragma unroll 6
        for (int r = 0; r < T_; ++r) acc += pas_s[r] * bf2f(qo[r][tid]);
        sem[(size_t)i * SEM_ + tid] = f2bf(acc);
    }
    if (tid < TD_) sem[(size_t)i * SEM_ + D_ + tid] = f2bf(topic_emb[(size_t)topic * TD_ + tid]);
}

// ---------------------------------------------------------------------------
// Batched additive-attention logits: 16 items per wave-tile, MFMA.
// Tiles: clk 400 | uagg 120 | nid 120 | nsem 120  (total 760 = 190 blocks)
// ---------------------------------------------------------------------------
template<int DIM, bool XBF>
__device__ __forceinline__ void agg_tile(
    const void* xrow_lane, const unsigned short* __restrict__ Wt,
    const float* __restrict__ b1, const float* __restrict__ w2, float b2,
    const int* __restrict__ maskp, int item0, float* __restrict__ logits,
    int lm, int lg)
{
    constexpr int KT = DIM / 32;
    const int kb = lg * 8;
    bf16x8 a[KT];
    if (XBF) {
        const unsigned short* xr = (const unsigned short*)xrow_lane;
        #pragma unroll
        for (int kt = 0; kt < KT; ++kt) a[kt] = *(const bf16x8*)(xr + kt * 32 + kb);
    } else {
        const float* xr = (const float*)xrow_lane;
        #pragma unroll
        for (int kt = 0; kt < KT; ++kt) a[kt] = pack8(xr + kt * 32 + kb);
    }
    float vs[4] = {0.f, 0.f, 0.f, 0.f};
    #pragma unroll
    for (int nt = 0; nt < 8; ++nt) {
        const unsigned short* wp = Wt + (size_t)(nt * 16 + lm) * DIM + kb;
        f32x4 acc = {0.f,0.f,0.f,0.f};
        #pragma unroll
        for (int kt = 0; kt < KT; ++kt)
            acc = MFMA16(a[kt], *(const bf16x8*)(wp + kt * 32), acc);
        float b1v = b1[nt * 16 + lm], w2v = w2[nt * 16 + lm];
        vs[0] += tanhf(acc[0] + b1v) * w2v;
        vs[1] += tanhf(acc[1] + b1v) * w2v;
        vs[2] += tanhf(acc[2] + b1v) * w2v;
        vs[3] += tanhf(acc[3] + b1v) * w2v;
    }
    #pragma unroll
    for (int d = 1; d < 16; d <<= 1) {
        vs[0] += __shfl_xor(vs[0], d); vs[1] += __shfl_xor(vs[1], d);
        vs[2] += __shfl_xor(vs[2], d); vs[3] += __shfl_xor(vs[3], d);
    }
    if (lm == 0) {
        #pragma unroll
        for (int r = 0; r < 4; ++r) {
            int item = item0 + lg * 4 + r;
            logits[item] = maskp[item] ? (vs[r] + b2) : -1e30f;
        }
    }
}

__global__ __launch_bounds__(256) void agg_logits_kernel(
    const unsigned short* __restrict__ sem,
    const float* __restrict__ user_emb, const float* __restrict__ news_emb,
    const int* __restrict__ neighbor_users, const int* __restrict__ neighbor_news,
    const int* __restrict__ clicked_mask, const int* __restrict__ neighbor_user_mask,
    const int* __restrict__ neighbor_news_mask,
    const unsigned short* __restrict__ WtClk, const unsigned short* __restrict__ WtU,
    const unsigned short* __restrict__ WtNid, const unsigned short* __restrict__ WtNsem,
    const float* __restrict__ clk_b1, const float* __restrict__ clk_w2, const float* __restrict__ clk_b2,
    const float* __restrict__ uagg_b1, const float* __restrict__ uagg_w2, const float* __restrict__ uagg_b2,
    const float* __restrict__ nid_b1, const float* __restrict__ nid_w2, const float* __restrict__ nid_b2,
    const float* __restrict__ nsem_b1, const float* __restrict__ nsem_w2, const float* __restrict__ nsem_b2,
    float* __restrict__ lg_clk, float* __restrict__ lg_u,
    float* __restrict__ lg_nid, float* __restrict__ lg_nsem)
{
    const int tid = threadIdx.x;
    const int l = tid & 63, w = tid >> 6;
    const int lm = l & 15, lg = l >> 4;
    const int gid = blockIdx.x * 4 + w;

    if (gid < 400) {
        int item0 = gid * 16;
        const unsigned short* xr = sem + (size_t)(item0 + lm) * SEM_;
        agg_tile<320, true>(xr, WtClk, clk_b1, clk_w2, clk_b2[0],
                            clicked_mask, item0, lg_clk, lm, lg);
    } else if (gid < 520) {
        int item0 = (gid - 400) * 16;
        const float* xr = user_emb + (size_t)neighbor_users[item0 + lm] * 128;
        agg_tile<128, false>(xr, WtU, uagg_b1, uagg_w2, uagg_b2[0],
                             neighbor_user_mask, item0, lg_u, lm, lg);
    } else if (gid < 640) {
        int item0 = (gid - 520) * 16;
        const float* xr = news_emb + (size_t)neighbor_news[item0 + lm] * 128;
        agg_tile<128, false>(xr, WtNid, nid_b1, nid_w2, nid_b2[0],
                             neighbor_news_mask, item0, lg_nid, lm, lg);
    } else {
        int item0 = (gid - 640) * 16;
        const unsigned short* xr = sem + (size_t)(6528 + item0 + lm) * SEM_;
        agg_tile<320, true>(xr, WtNsem, nsem_b1, nsem_w2, nsem_b2[0],
                            neighbor_news_mask, item0, lg_nsem, lm, lg);
    }
}

__device__ __forceinline__ float softmax_lane(float v, bool valid) {
    float m = v;
    #pragma unroll
    for (int d = 1; d < 64; d <<= 1) m = fmaxf(m, __shfl_xor(m, d));
    float e = valid ? __expf(v - m) : 0.f;
    float s = e;
    #pragma unroll
    for (int d = 1; d < 64; d <<= 1) s += __shfl_xor(s, d);
    return e / s;
}

// ---------------------------------------------------------------------------
// user_final: softmax(lc[50], lu[15]) + weighted sums + concat -> out[:, :576]
// ---------------------------------------------------------------------------
__global__ __launch_bounds__(576) void user_final(
    const float* __restrict__ lg_clk, const float* __restrict__ lg_u,
    const unsigned short* __restrict__ sem,
    const float* __restrict__ user_emb,
    const int* __restrict__ user_id, const int* __restrict__ neighbor_users,
    float* __restrict__ out)
{
    const int b = blockIdx.x;
    const int tid = threadIdx.x, w = tid >> 6, l = tid & 63;
    __shared__ float ac[C_];
    __shared__ float au[NU_ + 1];

    if (w == 0) {
        float v = (l < C_) ? lg_clk[b * C_ + l] : -1e30f;
        float a = softmax_lane(v, l < C_);
        if (l < C_) ac[l] = a;
    } else if (w == 1) {
        float v = (l < NU_) ? lg_u[b * NU_ + l] : -1e30f;
        float a = softmax_lane(v, l < NU_);
        if (l < NU_) au[l] = a;
    }
    __syncthreads();

    if (tid < SEM_) {
        float acc = 0.f;
        #pragma unroll 5
        for (int c = 0; c < C_; ++c)
            acc += ac[c] * bf2f(sem[(size_t)(b * C_ + c) * SEM_ + tid]);
        out[(size_t)b * 576 + tid] = acc;
    } else if (tid < 448) {
        int d = tid - SEM_;
        out[(size_t)b * 576 + tid] = user_emb[(size_t)user_id[b] * 128 + d];
    } else {
        int d = tid - 448;
        float acc = 0.f;
        #pragma unroll
        for (int n = 0; n < NU_; ++n)
            acc += au[n] * user_emb[(size_t)neighbor_users[b * NU_ + n] * 128 + d];
        out[(size_t)b * 576 + 448 + d] = acc;
    }
}

// ---------------------------------------------------------------------------
// news_final: softmax(li, ls) + build cat[896] bf16
// ---------------------------------------------------------------------------
__global__ __launch_bounds__(896) void news_final(
    const float* __restrict__ lg_nid, const float* __restrict__ lg_nsem,
    const unsigned short* __restrict__ sem,
    const float* __restrict__ news_emb,
    const int* __restrict__ candidate_news_id, const int* __restrict__ neighbor_news,
    unsigned short* __restrict__ cat)
{
    const int b = blockIdx.x;
    const int tid = threadIdx.x, w = tid >> 6, l = tid & 63;
    __shared__ float ai[NN_ + 1];
    __shared__ float as2[NN_ + 1];

    if (w == 0) {
        float v = (l < NN_) ? lg_nid[b * NN_ + l] : -1e30f;
        float a = softmax_lane(v, l < NN_);
        if (l < NN_) ai[l] = a;
    } else if (w == 1) {
        float v = (l < NN_) ? lg_nsem[b * NN_ + l] : -1e30f;
        float a = softmax_lane(v, l < NN_);
        if (l < NN_) as2[l] = a;
    }
    __syncthreads();

    unsigned short* cp = cat + (size_t)b * 896;
    if (tid < SEM_) {
        cp[tid] = sem[(size_t)(B_*C_ + b) * SEM_ + tid];
    } else if (tid < 448) {
        int d = tid - SEM_;
        cp[tid] = f2bf(news_emb[(size_t)candidate_news_id[b] * 128 + d]);
    } else if (tid < 576) {
        int d = tid - 448;
        float acc = 0.f;
        #pragma unroll
        for (int n = 0; n < NN_; ++n)
            acc += ai[n] * news_emb[(size_t)neighbor_news[b * NN_ + n] * 128 + d];
        cp[tid] = f2bf(acc);
    } else {
        int d = tid - 576;
        float acc = 0.f;
        #pragma unroll
        for (int n = 0; n < NN_; ++n)
            acc += as2[n] * bf2f(sem[(size_t)(6528 + b * NN_ + n) * SEM_ + d]);
        cp[tid] = f2bf(acc);
    }
}

// ---------------------------------------------------------------------------
// proj: news_repr = cat[128x896] @ proj_W + b  (288 wave-tiles)
// ---------------------------------------------------------------------------
__global__ __launch_bounds__(256) void proj_kernel(
    const unsigned short* __restrict__ cat, const unsigned short* __restrict__ projT,
    const float* __restrict__ proj_b, float* __restrict__ outp)
{
    const int tid = threadIdx.x;
    const int l = tid & 63, w = tid >> 6;
    const int lm = l & 15, lg = l >> 4;
    const int id = blockIdx.x * 4 + w;          // 0..287
    const int mt = id / 36, nt = id - mt * 36;
    const int kb = lg * 8;

    const unsigned short* ap = cat + (size_t)(mt * 16 + lm) * 896 + kb;
    const unsigned short* bp = projT + (size_t)(nt * 16 + lm) * 896 + kb;
    f32x4 acc = {0.f,0.f,0.f,0.f};
    #pragma unroll 7
    for (int kt = 0; kt < 28; ++kt)
        acc = MFMA16(*(const bf16x8*)(ap + kt * 32), *(const bf16x8*)(bp + kt * 32), acc);

    const int coln = nt * 16 + lm;
    const float pb = proj_b[coln];
    #pragma unroll
    for (int r = 0; r < 4; ++r) {
        int row = mt * 16 + lg * 4 + r;
        outp[(size_t)row * 576 + coln] = acc[r] + pb;
    }
}

extern "C" void kernel_launch(void* const* d_in, const int* in_sizes, int n_in,
                              void* d_out, int out_size, void* d_ws, size_t ws_size,
                              hipStream_t stream)
{
    const int* user_id            = (const int*)d_in[0];
    const int* candidate_news_id  = (const int*)d_in[1];
    const int* candidate_title    = (const int*)d_in[2];
    const int* candidate_topic    = (const int*)d_in[3];
    const int* clicked_title      = (const int*)d_in[4];
    const int* clicked_topic      = (const int*)d_in[5];
    const int* clicked_mask       = (const int*)d_in[6];
    const int* neighbor_users     = (const int*)d_in[7];
    const int* neighbor_user_mask = (const int*)d_in[8];
    const int* neighbor_news      = (const int*)d_in[9];
    const int* neighbor_news_mask = (const int*)d_in[10];
    const int* neighbor_title     = (const int*)d_in[11];
    const int* neighbor_topic     = (const int*)d_in[12];
    const float* user_emb  = (const float*)d_in[13];
    const float* news_emb  = (const float*)d_in[14];
    const float* word_emb  = (const float*)d_in[15];
    const float* topic_emb = (const float*)d_in[16];
    const float* Wq  = (const float*)d_in[17];
    const float* Wk  = (const float*)d_in[18];
    const float* Wv  = (const float*)d_in[19];
    const float* aW1 = (const float*)d_in[20];
    const float* ab1 = (const float*)d_in[21];
    const float* aw2 = (const float*)d_in[22];
    const float* clk_W1 = (const float*)d_in[23];
    const float* clk_b1 = (const float*)d_in[24];
    const float* clk_w2 = (const float*)d_in[25];
    const float* clk_b2 = (const float*)d_in[26];
    const float* uagg_W1 = (const float*)d_in[27];
    const float* uagg_b1 = (const float*)d_in[28];
    const float* uagg_w2 = (const float*)d_in[29];
    const float* uagg_b2 = (const float*)d_in[30];
    const float* nid_W1 = (const float*)d_in[31];
    const float* nid_b1 = (const float*)d_in[32];
    const float* nid_w2 = (const float*)d_in[33];
    const float* nid_b2 = (const float*)d_in[34];
    const float* nsem_W1 = (const float*)d_in[35];
    const float* nsem_b1 = (const float*)d_in[36];
    const float* nsem_w2 = (const float*)d_in[37];
    const float* nsem_b2 = (const float*)d_in[38];
    const float* proj_W = (const float*)d_in[39];
    const float* proj_b = (const float*)d_in[40];

    // ---- workspace layout (bytes) ----
    char* p = (char*)d_ws;
    unsigned short* sem    = (unsigned short*)p; p += (size_t)NSEQ_ * SEM_ * 2;   // 5,406,720
    unsigned short* WT     = (unsigned short*)p; p += 768 * 256 * 2;
    unsigned short* aW1T   = (unsigned short*)p; p += 128 * 256 * 2;
    unsigned short* WtClk  = (unsigned short*)p; p += 128 * 320 * 2;
    unsigned short* WtU    = (unsigned short*)p; p += 128 * 128 * 2;
    unsigned short* WtNid  = (unsigned short*)p; p += 128 * 128 * 2;
    unsigned short* WtNsem = (unsigned short*)p; p += 128 * 320 * 2;
    unsigned short* projT  = (unsigned short*)p; p += 576 * 896 * 2;
    float* lg_clk  = (float*)p; p += 6400 * 4;
    float* lg_u    = (float*)p; p += 1920 * 4;
    float* lg_nid  = (float*)p; p += 1920 * 4;
    float* lg_nsem = (float*)p; p += 1920 * 4;
    unsigned short* cat = (unsigned short*)p; p += 128 * 896 * 2;

    prep_kernel<<<(PREP_TOTAL + 255) / 256, 256, 0, stream>>>(
        Wq, Wk, Wv, aW1, clk_W1, uagg_W1, nid_W1, nsem_W1, proj_W,
        WT, aW1T, WtClk, WtU, WtNid, WtNsem, projT);

    tf_core<<<NSEQ_, 256, 0, stream>>>(clicked_title, clicked_topic,
        candidate_title, candidate_topic, neighbor_title, neighbor_topic,
        word_emb, topic_emb, WT, aW1T, ab1, aw2, sem);

    agg_logits_kernel<<<190, 256, 0, stream>>>(sem, user_emb, news_emb,
        neighbor_users, neighbor_news,
        clicked_mask, neighbor_user_mask, neighbor_news_mask,
        WtClk, WtU, WtNid, WtNsem,
        clk_b1, clk_w2, clk_b2, uagg_b1, uagg_w2, uagg_b2,
        nid_b1, nid_w2, nid_b2, nsem_b1, nsem_w2, nsem_b2,
        lg_clk, lg_u, lg_nid, lg_nsem);

    user_final<<<B_, 576, 0, stream>>>(lg_clk, lg_u, sem, user_emb,
        user_id, neighbor_users, (float*)d_out);

    news_final<<<B_, 896, 0, stream>>>(lg_nid, lg_nsem, sem, news_emb,
        candidate_news_id, neighbor_news, cat);

    proj_kernel<<<72, 256, 0, stream>>>(cat, projT, proj_b,
        (float*)d_out + (size_t)B_ * 576);
}

// Round 4
// 798.167 us; speedup vs baseline: 11.0280x; 1.0982x over previous
//
#include <hip/hip_runtime.h>
#include <hip/hip_bf16.h>
#include <math.h>

#define T_ 30
#define D_ 256
#define H_ 8
#define DH_ 32
#define HID_ 128
#define TD_ 64
#define SEM_ 320
#define B_ 128
#define C_ 50
#define NN_ 15
#define NU_ 15
#define NSEQ_ (B_*C_ + B_ + B_*NN_)   /* 8448 */

typedef short bf16x8 __attribute__((ext_vector_type(8)));
typedef float f32x4 __attribute__((ext_vector_type(4)));
#define MFMA16(a,b,c) __builtin_amdgcn_mfma_f32_16x16x32_bf16(a,b,c,0,0,0)

__device__ __forceinline__ unsigned short f2bf(float f) {
    union { float f; unsigned u; } v; v.f = f;
    unsigned u = v.u;
    u += 0x7FFFu + ((u >> 16) & 1u);      // RTNE
    return (unsigned short)(u >> 16);
}
__device__ __forceinline__ float bf2f(unsigned short s) {
    union { unsigned u; float f; } v; v.u = ((unsigned)s) << 16; return v.f;
}
__device__ __forceinline__ bf16x8 pack8(const float* p) {
    const float4 a = *(const float4*)p;
    const float4 b = *(const float4*)(p + 4);
    bf16x8 r;
    r[0]=(short)f2bf(a.x); r[1]=(short)f2bf(a.y); r[2]=(short)f2bf(a.z); r[3]=(short)f2bf(a.w);
    r[4]=(short)f2bf(b.x); r[5]=(short)f2bf(b.y); r[6]=(short)f2bf(b.z); r[7]=(short)f2bf(b.w);
    return r;
}

// ---------------------------------------------------------------------------
// Prep (read-coalesced): WT[768][256] <- [Wq|Wk|Wv]^T ; aW1T[128][256] ;
// WtClk[128][320] ; WtU[128][128] ; WtNid[128][128] ; WtNsem[128][320] ;
// projT[576][896]
// ---------------------------------------------------------------------------
#define PREP_TOTAL (196608 + 32768 + 40960 + 16384 + 16384 + 40960 + 516096)
__global__ __launch_bounds__(256) void prep_kernel(
    const float* __restrict__ Wq, const float* __restrict__ Wk,
    const float* __restrict__ Wv, const float* __restrict__ aW1,
    const float* __restrict__ clk_W1, const float* __restrict__ uagg_W1,
    const float* __restrict__ nid_W1, const float* __restrict__ nsem_W1,
    const float* __restrict__ proj_W,
    unsigned short* __restrict__ WT, unsigned short* __restrict__ aW1T,
    unsigned short* __restrict__ WtClk, unsigned short* __restrict__ WtU,
    unsigned short* __restrict__ WtNid, unsigned short* __restrict__ WtNsem,
    unsigned short* __restrict__ projT)
{
    int idx = blockIdx.x * 256 + threadIdx.x;
    if (idx < 65536) {                                   // Wq
        int k = idx >> 8, n = idx & 255;
        WT[n * 256 + k] = f2bf(Wq[idx]);
    } else if (idx < 131072) {                           // Wk
        int s = idx - 65536; int k = s >> 8, n = s & 255;
        WT[(n + 256) * 256 + k] = f2bf(Wk[s]);
    } else if (idx < 196608) {                           // Wv
        int s = idx - 131072; int k = s >> 8, n = s & 255;
        WT[(n + 512) * 256 + k] = f2bf(Wv[s]);
    } else if (idx < 196608 + 32768) {                   // aW1
        int s = idx - 196608; int k = s >> 7, n = s & 127;
        aW1T[n * 256 + k] = f2bf(aW1[s]);
    } else if (idx < 229376 + 40960) {                   // clk_W1 [320][128]
        int s = idx - 229376; int k = s >> 7, n = s & 127;
        WtClk[n * 320 + k] = f2bf(clk_W1[s]);
    } else if (idx < 270336 + 16384) {                   // uagg_W1 [128][128]
        int s = idx - 270336; int k = s >> 7, n = s & 127;
        WtU[n * 128 + k] = f2bf(uagg_W1[s]);
    } else if (idx < 286720 + 16384) {                   // nid_W1
        int s = idx - 286720; int k = s >> 7, n = s & 127;
        WtNid[n * 128 + k] = f2bf(nid_W1[s]);
    } else if (idx < 303104 + 40960) {                   // nsem_W1 [320][128]
        int s = idx - 303104; int k = s >> 7, n = s & 127;
        WtNsem[n * 320 + k] = f2bf(nsem_W1[s]);
    } else if (idx < PREP_TOTAL) {                       // proj_W [896][576]
        int s = idx - 344064; int k = s / 576, n = s - k * 576;
        projT[(size_t)n * 896 + k] = f2bf(proj_W[s]);
    }
}

// ---------------------------------------------------------------------------
// tf_core: one block (4 waves) per sequence. LDS = 50176 B -> 3 blocks/CU.
// ---------------------------------------------------------------------------
__global__ __launch_bounds__(256, 3) void tf_core(
    const int* __restrict__ clicked_title, const int* __restrict__ clicked_topic,
    const int* __restrict__ candidate_title, const int* __restrict__ candidate_topic,
    const int* __restrict__ neighbor_title, const int* __restrict__ neighbor_topic,
    const float* __restrict__ word_emb, const float* __restrict__ topic_emb,
    const unsigned short* __restrict__ WT, const unsigned short* __restrict__ aW1T,
    const float* __restrict__ ab1, const float* __restrict__ aw2,
    unsigned short* __restrict__ sem)
{
    __shared__ __align__(16) unsigned short qo[32][264];   // Q, then O (aliased)
    __shared__ __align__(16) unsigned short kp[32][264];   // K, then per-wave P + pls/pas
    __shared__ __align__(16) unsigned short vt[256][32];   // V^T [dcol][token], 16384 B

    float* pls_part = (float*)(&kp[0][0]);                 // [4][32], after K/P dead
    float* pas_s    = (float*)((char*)(&kp[0][0]) + 512);  // [32]

    const int tid = threadIdx.x;
    const int l = tid & 63, w = tid >> 6;
    const int lm = l & 15, lg = l >> 4;
    const int rbase = lg * 4;
    const int kb = lg * 8;
    const int i = blockIdx.x;

    const int* tok; int topic;
    if (i < B_*C_)            { tok = clicked_title   + i*T_;               topic = clicked_topic[i]; }
    else if (i < B_*C_ + B_)  { int j = i - B_*C_;      tok = candidate_title + j*T_; topic = candidate_topic[j]; }
    else                      { int j = i - (B_*C_+B_); tok = neighbor_title  + j*T_; topic = neighbor_topic[j]; }

    // ---- A-fragments of x (rows 30/31 zero) ----
    bf16x8 afrag[2][8];
    #pragma unroll
    for (int mt = 0; mt < 2; ++mt) {
        int row = mt * 16 + lm;
        if (row < T_) {
            const float* xr = word_emb + (size_t)tok[row] * D_;
            #pragma unroll
            for (int kt = 0; kt < 8; ++kt)
                afrag[mt][kt] = pack8(xr + kt * 32 + kb);
        } else {
            #pragma unroll
            for (int kt = 0; kt < 8; ++kt) {
                bf16x8 z;
                #pragma unroll
                for (int e = 0; e < 8; ++e) z[e] = 0;
                afrag[mt][kt] = z;
            }
        }
    }

    // ---- QKV GEMM: wave w handles N-tiles 12w..12w+11; half-tile dbuf ----
    {
        const unsigned short* wtb = WT + (size_t)lm * 256 + kb;
        bf16x8 bufA[4], bufB[4];
        f32x4 acc0, acc1;

        #define LOADH(buf, h_) { \
            const unsigned short* p_ = wtb + (size_t)((w * 12 + ((h_) >> 1)) * 16) * 256 + ((h_) & 1) * 128; \
            buf[0] = *(const bf16x8*)(p_);      buf[1] = *(const bf16x8*)(p_ + 32); \
            buf[2] = *(const bf16x8*)(p_ + 64); buf[3] = *(const bf16x8*)(p_ + 96); }
        #define CONSUME(buf, h_) { \
            const int kt0_ = ((h_) & 1) * 4; \
            acc0 = MFMA16(afrag[0][kt0_+0], buf[0], acc0); acc1 = MFMA16(afrag[1][kt0_+0], buf[0], acc1); \
            acc0 = MFMA16(afrag[0][kt0_+1], buf[1], acc0); acc1 = MFMA16(afrag[1][kt0_+1], buf[1], acc1); \
            acc0 = MFMA16(afrag[0][kt0_+2], buf[2], acc0); acc1 = MFMA16(afrag[1][kt0_+2], buf[2], acc1); \
            acc0 = MFMA16(afrag[0][kt0_+3], buf[3], acc0); acc1 = MFMA16(afrag[1][kt0_+3], buf[3], acc1); }

        LOADH(bufA, 0);
        #pragma unroll
        for (int t = 0; t < 12; ++t) {
            acc0 = (f32x4){0.f,0.f,0.f,0.f};
            acc1 = (f32x4){0.f,0.f,0.f,0.f};
            LOADH(bufB, 2*t + 1);
            CONSUME(bufA, 2*t);
            if (t < 11) LOADH(bufA, 2*t + 2);
            CONSUME(bufB, 2*t + 1);
            {
                const int n0 = (w * 12 + t) * 16;
                const int which = n0 >> 8;
                const int lc = (n0 + lm) & 255;
                if (which == 0) {
                    #pragma unroll
                    for (int r = 0; r < 4; ++r) {
                        qo[rbase + r][lc]      = f2bf(acc0[r]);
                        qo[16 + rbase + r][lc] = f2bf(acc1[r]);
                    }
                } else if (which == 1) {
                    #pragma unroll
                    for (int r = 0; r < 4; ++r) {
                        kp[rbase + r][lc]      = f2bf(acc0[r]);
                        kp[16 + rbase + r][lc] = f2bf(acc1[r]);
                    }
                } else {
                    unsigned lo0 = (unsigned)f2bf(acc0[0]) | ((unsigned)f2bf(acc0[1]) << 16);
                    unsigned hi0 = (unsigned)f2bf(acc0[2]) | ((unsigned)f2bf(acc0[3]) << 16);
                    unsigned lo1 = (unsigned)f2bf(acc1[0]) | ((unsigned)f2bf(acc1[1]) << 16);
                    unsigned hi1 = (unsigned)f2bf(acc1[2]) | ((unsigned)f2bf(acc1[3]) << 16);
                    *(unsigned*)&vt[lc][rbase]          = lo0;
                    *(unsigned*)&vt[lc][rbase + 2]      = hi0;
                    *(unsigned*)&vt[lc][16 + rbase]     = lo1;
                    *(unsigned*)&vt[lc][16 + rbase + 2] = hi1;
                }
            }
        }
        #undef LOADH
        #undef CONSUME
    }
    __syncthreads();

    // ---- Attention: 2 heads/wave; P reuses dead K cols [64w..64w+31] ----
    const float sc = 0.17677669529663687f;   // 1/sqrt(32)
    const int pcb = w * 64;
    #pragma unroll
    for (int hh = 0; hh < 2; ++hh) {
        const int h = 2 * w + hh, cb = h * DH_;
        bf16x8 aq0 = *(const bf16x8*)&qo[lm][cb + kb];
        bf16x8 aq1 = *(const bf16x8*)&qo[16 + lm][cb + kb];
        bf16x8 bk0 = *(const bf16x8*)&kp[lm][cb + kb];
        bf16x8 bk1 = *(const bf16x8*)&kp[16 + lm][cb + kb];
        f32x4 z = {0.f,0.f,0.f,0.f};
        f32x4 s00 = MFMA16(aq0, bk0, z);
        f32x4 s01 = MFMA16(aq0, bk1, z);
        f32x4 s10 = MFMA16(aq1, bk0, z);
        f32x4 s11 = MFMA16(aq1, bk1, z);
        #pragma unroll
        for (int r = 0; r < 4; ++r) {
            s00[r] *= sc; s01[r] *= sc; s10[r] *= sc; s11[r] *= sc;
            if (lm >= 14) { s01[r] = -1e30f; s11[r] = -1e30f; }   // keys 30,31
        }
        #pragma unroll
        for (int r = 0; r < 4; ++r) {
            float mx0 = fmaxf(s00[r], s01[r]);
            float mx1 = fmaxf(s10[r], s11[r]);
            #pragma unroll
            for (int d = 1; d < 16; d <<= 1) {
                mx0 = fmaxf(mx0, __shfl_xor(mx0, d));
                mx1 = fmaxf(mx1, __shfl_xor(mx1, d));
            }
            float e00 = __expf(s00[r] - mx0), e01 = __expf(s01[r] - mx0);
            float e10 = __expf(s10[r] - mx1), e11 = __expf(s11[r] - mx1);
            float sm0 = e00 + e01, sm1 = e10 + e11;
            #pragma unroll
            for (int d = 1; d < 16; d <<= 1) {
                sm0 += __shfl_xor(sm0, d);
                sm1 += __shfl_xor(sm1, d);
            }
            float inv0 = 1.f / sm0, inv1 = 1.f / sm1;
            kp[rbase + r][pcb + lm]           = f2bf(e00 * inv0);
            kp[rbase + r][pcb + 16 + lm]      = f2bf(e01 * inv0);
            kp[16 + rbase + r][pcb + lm]      = f2bf(e10 * inv1);
            kp[16 + rbase + r][pcb + 16 + lm] = f2bf(e11 * inv1);
        }
        bf16x8 ap0 = *(const bf16x8*)&kp[lm][pcb + kb];
        bf16x8 ap1 = *(const bf16x8*)&kp[16 + lm][pcb + kb];
        bf16x8 bv0 = *(const bf16x8*)&vt[cb + lm][kb];
        bf16x8 bv1 = *(const bf16x8*)&vt[cb + 16 + lm][kb];
        f32x4 o00 = MFMA16(ap0, bv0, z);
        f32x4 o01 = MFMA16(ap0, bv1, z);
        f32x4 o10 = MFMA16(ap1, bv0, z);
        f32x4 o11 = MFMA16(ap1, bv1, z);
        #pragma unroll
        for (int r = 0; r < 4; ++r) {
            qo[rbase + r][cb + lm]           = f2bf(o00[r]);
            qo[rbase + r][cb + 16 + lm]      = f2bf(o01[r]);
            qo[16 + rbase + r][cb + lm]      = f2bf(o10[r]);
            qo[16 + rbase + r][cb + 16 + lm] = f2bf(o11[r]);
        }
    }
    __syncthreads();

    // ---- Pooling GEMM (half-K dbuf): wave w -> hidden cols [32w..32w+31] ----
    {
        f32x4 h00 = {0.f,0.f,0.f,0.f}, h01 = h00, h10 = h00, h11 = h00;
        const unsigned short* w0p = aW1T + (size_t)(w * 32 + lm) * 256 + kb;
        const unsigned short* w1p = aW1T + (size_t)(w * 32 + 16 + lm) * 256 + kb;
        bf16x8 bw0a = *(const bf16x8*)(w0p);
        bf16x8 bw1a = *(const bf16x8*)(w1p);
        bf16x8 bw0b, bw1b;
        #pragma unroll
        for (int kt = 0; kt < 8; ++kt) {
            if (kt + 1 < 8) {
                if (kt & 1) { bw0a = *(const bf16x8*)(w0p + (kt+1) * 32); bw1a = *(const bf16x8*)(w1p + (kt+1) * 32); }
                else        { bw0b = *(const bf16x8*)(w0p + (kt+1) * 32); bw1b = *(const bf16x8*)(w1p + (kt+1) * 32); }
            }
            bf16x8 ao0 = *(const bf16x8*)&qo[lm][kt * 32 + kb];
            bf16x8 ao1 = *(const bf16x8*)&qo[16 + lm][kt * 32 + kb];
            bf16x8 b0 = (kt & 1) ? bw0b : bw0a;
            bf16x8 b1 = (kt & 1) ? bw1b : bw1a;
            h00 = MFMA16(ao0, b0, h00);
            h01 = MFMA16(ao0, b1, h01);
            h10 = MFMA16(ao1, b0, h10);
            h11 = MFMA16(ao1, b1, h11);
        }
        const int c0 = w * 32 + lm, c1 = c0 + 16;
        const float b0 = ab1[c0], b1 = ab1[c1];
        const float a20 = aw2[c0], a21 = aw2[c1];
        float vsum[4];
        #pragma unroll
        for (int r = 0; r < 4; ++r) {
            float v0 = tanhf(h00[r] + b0) * a20 + tanhf(h01[r] + b1) * a21;
            float v1 = tanhf(h10[r] + b0) * a20 + tanhf(h11[r] + b1) * a21;
            #pragma unroll
            for (int d = 1; d < 16; d <<= 1) {
                v0 += __shfl_xor(v0, d);
                v1 += __shfl_xor(v1, d);
            }
            vsum[r] = v0;
            if (lm == 0) pls_part[w * 32 + 16 + rbase + r] = v1;
        }
        #pragma unroll
        for (int r = 0; r < 4; ++r)
            if (lm == 0) pls_part[w * 32 + rbase + r] = __shfl(vsum[r], lg * 16);
    }
    __syncthreads();

    // ---- final softmax over 30 (wave 0, parallel) ----
    if (w == 0) {
        float pl = -1e30f;
        if (l < T_) pl = pls_part[l] + pls_part[32 + l] + pls_part[64 + l] + pls_part[96 + l];
        float m = pl;
        #pragma unroll
        for (int d = 1; d < 64; d <<= 1) m = fmaxf(m, __shfl_xor(m, d));
        float e = (l < T_) ? __expf(pl - m) : 0.f;
        float s = e;
        #pragma unroll
        for (int d = 1; d < 64; d <<= 1) s += __shfl_xor(s, d);
        if (l < 32) pas_s[l] = e / s;
    }
    __syncthreads();

    // ---- title = pa @ o (bf16 out); concat topic ----
    {
        float acc = 0.f;
        #pragma unroll 6
        for (int r = 0; r < T_; ++r) acc += pas_s[r] * bf2f(qo[r][tid]);
        sem[(size_t)i * SEM_ + tid] = f2bf(acc);
    }
    if (tid < TD_) sem[(size_t)i * SEM_ + D_ + tid] = f2bf(topic_emb[(size_t)topic * TD_ + tid]);
}

// ---------------------------------------------------------------------------
// Batched additive-attention logits (unchanged)
// ---------------------------------------------------------------------------
template<int DIM, bool XBF>
__device__ __forceinline__ void agg_tile(
    const void* xrow_lane, const unsigned short* __restrict__ Wt,
    const float* __restrict__ b1, const float* __restrict__ w2, float b2,
    const int* __restrict__ maskp, int item0, float* __restrict__ logits,
    int lm, int lg)
{
    constexpr int KT = DIM / 32;
    const int kb = lg * 8;
    bf16x8 a[KT];
    if (XBF) {
        const unsigned short* xr = (const unsigned short*)xrow_lane;
        #pragma unroll
        for (int kt = 0; kt < KT; ++kt) a[kt] = *(const bf16x8*)(xr + kt * 32 + kb);
    } else {
        const float* xr = (const float*)xrow_lane;
        #pragma unroll
        for (int kt = 0; kt < KT; ++kt) a[kt] = pack8(xr + kt * 32 + kb);
    }
    float vs[4] = {0.f, 0.f, 0.f, 0.f};
    #pragma unroll
    for (int nt = 0; nt < 8; ++nt) {
        const unsigned short* wp = Wt + (size_t)(nt * 16 + lm) * DIM + kb;
        f32x4 acc = {0.f,0.f,0.f,0.f};
        #pragma unroll
        for (int kt = 0; kt < KT; ++kt)
            acc = MFMA16(a[kt], *(const bf16x8*)(wp + kt * 32), acc);
        float b1v = b1[nt * 16 + lm], w2v = w2[nt * 16 + lm];
        vs[0] += tanhf(acc[0] + b1v) * w2v;
        vs[1] += tanhf(acc[1] + b1v) * w2v;
        vs[2] += tanhf(acc[2] + b1v) * w2v;
        vs[3] += tanhf(acc[3] + b1v) * w2v;
    }
    #pragma unroll
    for (int d = 1; d < 16; d <<= 1) {
        vs[0] += __shfl_xor(vs[0], d); vs[1] += __shfl_xor(vs[1], d);
        vs[2] += __shfl_xor(vs[2], d); vs[3] += __shfl_xor(vs[3], d);
    }
    if (lm == 0) {
        #pragma unroll
        for (int r = 0; r < 4; ++r) {
            int item = item0 + lg * 4 + r;
            logits[item] = maskp[item] ? (vs[r] + b2) : -1e30f;
        }
    }
}

__global__ __launch_bounds__(256) void agg_logits_kernel(
    const unsigned short* __restrict__ sem,
    const float* __restrict__ user_emb, const float* __restrict__ news_emb,
    const int* __restrict__ neighbor_users, const int* __restrict__ neighbor_news,
    const int* __restrict__ clicked_mask, const int* __restrict__ neighbor_user_mask,
    const int* __restrict__ neighbor_news_mask,
    const unsigned short* __restrict__ WtClk, const unsigned short* __restrict__ WtU,
    const unsigned short* __restrict__ WtNid, const unsigned short* __restrict__ WtNsem,
    const float* __restrict__ clk_b1, const float* __restrict__ clk_w2, const float* __restrict__ clk_b2,
    const float* __restrict__ uagg_b1, const float* __restrict__ uagg_w2, const float* __restrict__ uagg_b2,
    const float* __restrict__ nid_b1, const float* __restrict__ nid_w2, const float* __restrict__ nid_b2,
    const float* __restrict__ nsem_b1, const float* __restrict__ nsem_w2, const float* __restrict__ nsem_b2,
    float* __restrict__ lg_clk, float* __restrict__ lg_u,
    float* __restrict__ lg_nid, float* __restrict__ lg_nsem)
{
    const int tid = threadIdx.x;
    const int l = tid & 63, w = tid >> 6;
    const int lm = l & 15, lg = l >> 4;
    const int gid = blockIdx.x * 4 + w;

    if (gid < 400) {
        int item0 = gid * 16;
        const unsigned short* xr = sem + (size_t)(item0 + lm) * SEM_;
        agg_tile<320, true>(xr, WtClk, clk_b1, clk_w2, clk_b2[0],
                            clicked_mask, item0, lg_clk, lm, lg);
    } else if (gid < 520) {
        int item0 = (gid - 400) * 16;
        const float* xr = user_emb + (size_t)neighbor_users[item0 + lm] * 128;
        agg_tile<128, false>(xr, WtU, uagg_b1, uagg_w2, uagg_b2[0],
                             neighbor_user_mask, item0, lg_u, lm, lg);
    } else if (gid < 640) {
        int item0 = (gid - 520) * 16;
        const float* xr = news_emb + (size_t)neighbor_news[item0 + lm] * 128;
        agg_tile<128, false>(xr, WtNid, nid_b1, nid_w2, nid_b2[0],
                             neighbor_news_mask, item0, lg_nid, lm, lg);
    } else {
        int item0 = (gid - 640) * 16;
        const unsigned short* xr = sem + (size_t)(6528 + item0 + lm) * SEM_;
        agg_tile<320, true>(xr, WtNsem, nsem_b1, nsem_w2, nsem_b2[0],
                            neighbor_news_mask, item0, lg_nsem, lm, lg);
    }
}

__device__ __forceinline__ float softmax_lane(float v, bool valid) {
    float m = v;
    #pragma unroll
    for (int d = 1; d < 64; d <<= 1) m = fmaxf(m, __shfl_xor(m, d));
    float e = valid ? __expf(v - m) : 0.f;
    float s = e;
    #pragma unroll
    for (int d = 1; d < 64; d <<= 1) s += __shfl_xor(s, d);
    return e / s;
}

// ---------------------------------------------------------------------------
// finals (merged): blocks 0..127 user branch -> out[:,:576];
//                  blocks 128..255 news branch -> cat[896] bf16
// ---------------------------------------------------------------------------
__global__ __launch_bounds__(896) void finals_kernel(
    const float* __restrict__ lg_clk, const float* __restrict__ lg_u,
    const float* __restrict__ lg_nid, const float* __restrict__ lg_nsem,
    const unsigned short* __restrict__ sem,
    const float* __restrict__ user_emb, const float* __restrict__ news_emb,
    const int* __restrict__ user_id, const int* __restrict__ neighbor_users,
    const int* __restrict__ candidate_news_id, const int* __restrict__ neighbor_news,
    float* __restrict__ out, unsigned short* __restrict__ cat)
{
    const int tid = threadIdx.x, w = tid >> 6, l = tid & 63;
    __shared__ float a0s[C_];
    __shared__ float a1s[NU_ + 1];

    if (blockIdx.x < B_) {
        const int b = blockIdx.x;
        if (w == 0) {
            float v = (l < C_) ? lg_clk[b * C_ + l] : -1e30f;
            float a = softmax_lane(v, l < C_);
            if (l < C_) a0s[l] = a;
        } else if (w == 1) {
            float v = (l < NU_) ? lg_u[b * NU_ + l] : -1e30f;
            float a = softmax_lane(v, l < NU_);
            if (l < NU_) a1s[l] = a;
        }
        __syncthreads();
        if (tid < SEM_) {
            float acc = 0.f;
            #pragma unroll 5
            for (int c = 0; c < C_; ++c)
                acc += a0s[c] * bf2f(sem[(size_t)(b * C_ + c) * SEM_ + tid]);
            out[(size_t)b * 576 + tid] = acc;
        } else if (tid < 448) {
            int d = tid - SEM_;
            out[(size_t)b * 576 + tid] = user_emb[(size_t)user_id[b] * 128 + d];
        } else if (tid < 576) {
            int d = tid - 448;
            float acc = 0.f;
            #pragma unroll
            for (int n = 0; n < NU_; ++n)
                acc += a1s[n] * user_emb[(size_t)neighbor_users[b * NU_ + n] * 128 + d];
            out[(size_t)b * 576 + 448 + d] = acc;
        }
    } else {
        const int b = blockIdx.x - B_;
        if (w == 0) {
            float v = (l < NN_) ? lg_nid[b * NN_ + l] : -1e30f;
            float a = softmax_lane(v, l < NN_);
            if (l < NN_) a0s[l] = a;
        } else if (w == 1) {
            float v = (l < NN_) ? lg_nsem[b * NN_ + l] : -1e30f;
            float a = softmax_lane(v, l < NN_);
            if (l < NN_) a1s[l] = a;
        }
        __syncthreads();
        unsigned short* cp = cat + (size_t)b * 896;
        if (tid < SEM_) {
            cp[tid] = sem[(size_t)(B_*C_ + b) * SEM_ + tid];
        } else if (tid < 448) {
            int d = tid - SEM_;
            cp[tid] = f2bf(news_emb[(size_t)candidate_news_id[b] * 128 + d]);
        } else if (tid < 576) {
            int d = tid - 448;
            float acc = 0.f;
            #pragma unroll
            for (int n = 0; n < NN_; ++n)
                acc += a0s[n] * news_emb[(size_t)neighbor_news[b * NN_ + n] * 128 + d];
            cp[tid] = f2bf(acc);
        } else {
            int d = tid - 576;
            float acc = 0.f;
            #pragma unroll
            for (int n = 0; n < NN_; ++n)
                acc += a1s[n] * bf2f(sem[(size_t)(6528 + b * NN_ + n) * SEM_ + d]);
            cp[tid] = f2bf(acc);
        }
    }
}

// ---------------------------------------------------------------------------
// proj: news_repr = cat[128x896] @ proj_W + b  (288 wave-tiles)
// ---------------------------------------------------------------------------
__global__ __launch_bounds__(256) void proj_kernel(
    const unsigned short* __restrict__ cat, const unsigned short* __restrict__ projT,
    const float* __restrict__ proj_b, float* __restrict__ outp)
{
    const int tid = threadIdx.x;
    const int l = tid & 63, w = tid >> 6;
    const int lm = l & 15, lg = l >> 4;
    const int id = blockIdx.x * 4 + w;          // 0..287
    const int mt = id / 36, nt = id - mt * 36;
    const int kb = lg * 8;

    const unsigned short* ap = cat + (size_t)(mt * 16 + lm) * 896 + kb;
    const unsigned short* bp = projT + (size_t)(nt * 16 + lm) * 896 + kb;
    f32x4 acc = {0.f,0.f,0.f,0.f};
    #pragma unroll 7
    for (int kt = 0; kt < 28; ++kt)
        acc = MFMA16(*(const bf16x8*)(ap + kt * 32), *(const bf16x8*)(bp + kt * 32), acc);

    const int coln = nt * 16 + lm;
    const float pb = proj_b[coln];
    #pragma unroll
    for (int r = 0; r < 4; ++r) {
        int row = mt * 16 + lg * 4 + r;
        outp[(size_t)row * 576 + coln] = acc[r] + pb;
    }
}

extern "C" void kernel_launch(void* const* d_in, const int* in_sizes, int n_in,
                              void* d_out, int out_size, void* d_ws, size_t ws_size,
                              hipStream_t stream)
{
    const int* user_id            = (const int*)d_in[0];
    const int* candidate_news_id  = (const int*)d_in[1];
    const int* candidate_title    = (const int*)d_in[2];
    const int* candidate_topic    = (const int*)d_in[3];
    const int* clicked_title      = (const int*)d_in[4];
    const int* clicked_topic      = (const int*)d_in[5];
    const int* clicked_mask       = (const int*)d_in[6];
    const int* neighbor_users     = (const int*)d_in[7];
    const int* neighbor_user_mask = (const int*)d_in[8];
    const int* neighbor_news      = (const int*)d_in[9];
    const int* neighbor_news_mask = (const int*)d_in[10];
    const int* neighbor_title     = (const int*)d_in[11];
    const int* neighbor_topic     = (const int*)d_in[12];
    const float* user_emb  = (const float*)d_in[13];
    const float* news_emb  = (const float*)d_in[14];
    const float* word_emb  = (const float*)d_in[15];
    const float* topic_emb = (const float*)d_in[16];
    const float* Wq  = (const float*)d_in[17];
    const float* Wk  = (const float*)d_in[18];
    const float* Wv  = (const float*)d_in[19];
    const float* aW1 = (const float*)d_in[20];
    const float* ab1 = (const float*)d_in[21];
    const float* aw2 = (const float*)d_in[22];
    const float* clk_W1 = (const float*)d_in[23];
    const float* clk_b1 = (const float*)d_in[24];
    const float* clk_w2 = (const float*)d_in[25];
    const float* clk_b2 = (const float*)d_in[26];
    const float* uagg_W1 = (const float*)d_in[27];
    const float* uagg_b1 = (const float*)d_in[28];
    const float* uagg_w2 = (const float*)d_in[29];
    const float* uagg_b2 = (const float*)d_in[30];
    const float* nid_W1 = (const float*)d_in[31];
    const float* nid_b1 = (const float*)d_in[32];
    const float* nid_w2 = (const float*)d_in[33];
    const float* nid_b2 = (const float*)d_in[34];
    const float* nsem_W1 = (const float*)d_in[35];
    const float* nsem_b1 = (const float*)d_in[36];
    const float* nsem_w2 = (const float*)d_in[37];
    const float* nsem_b2 = (const float*)d_in[38];
    const float* proj_W = (const float*)d_in[39];
    const float* proj_b = (const float*)d_in[40];

    // ---- workspace layout (bytes) ----
    char* p = (char*)d_ws;
    unsigned short* sem    = (unsigned short*)p; p += (size_t)NSEQ_ * SEM_ * 2;
    unsigned short* WT     = (unsigned short*)p; p += 768 * 256 * 2;
    unsigned short* aW1T   = (unsigned short*)p; p += 128 * 256 * 2;
    unsigned short* WtClk  = (unsigned short*)p; p += 128 * 320 * 2;
    unsigned short* WtU    = (unsigned short*)p; p += 128 * 128 * 2;
    unsigned short* WtNid  = (unsigned short*)p; p += 128 * 128 * 2;
    unsigned short* WtNsem = (unsigned short*)p; p += 128 * 320 * 2;
    unsigned short* projT  = (unsigned short*)p; p += 576 * 896 * 2;
    float* lg_clk  = (float*)p; p += 6400 * 4;
    float* lg_u    = (float*)p; p += 1920 * 4;
    float* lg_nid  = (float*)p; p += 1920 * 4;
    float* lg_nsem = (float*)p; p += 1920 * 4;
    unsigned short* cat = (unsigned short*)p; p += 128 * 896 * 2;

    prep_kernel<<<(PREP_TOTAL + 255) / 256, 256, 0, stream>>>(
        Wq, Wk, Wv, aW1, clk_W1, uagg_W1, nid_W1, nsem_W1, proj_W,
        WT, aW1T, WtClk, WtU, WtNid, WtNsem, projT);

    tf_core<<<NSEQ_, 256, 0, stream>>>(clicked_title, clicked_topic,
        candidate_title, candidate_topic, neighbor_title, neighbor_topic,
        word_emb, topic_emb, WT, aW1T, ab1, aw2, sem);

    agg_logits_kernel<<<190, 256, 0, stream>>>(sem, user_emb, news_emb,
        neighbor_users, neighbor_news,
        clicked_mask, neighbor_user_mask, neighbor_news_mask,
        WtClk, WtU, WtNid, WtNsem,
        clk_b1, clk_w2, clk_b2, uagg_b1, uagg_w2, uagg_b2,
        nid_b1, nid_w2, nid_b2, nsem_b1, nsem_w2, nsem_b2,
        lg_clk, lg_u, lg_nid, lg_nsem);

    finals_kernel<<<256, 896, 0, stream>>>(lg_clk, lg_u, lg_nid, lg_nsem,
        sem, user_emb, news_emb, user_id, neighbor_users,
        candidate_news_id, neighbor_news,
        (float*)d_out, cat);

    proj_kernel<<<72, 256, 0, stream>>>(cat, projT, proj_b,
        (float*)d_out + (size_t)B_ * 576);
}

// Round 6
// 795.319 us; speedup vs baseline: 11.0675x; 1.0036x over previous
//
#include <hip/hip_runtime.h>
#include <hip/hip_bf16.h>
#include <math.h>

#define T_ 30
#define D_ 256
#define H_ 8
#define DH_ 32
#define HID_ 128
#define TD_ 64
#define SEM_ 320
#define B_ 128
#define C_ 50
#define NN_ 15
#define NU_ 15
#define NSEQ_ (B_*C_ + B_ + B_*NN_)   /* 8448 */

typedef short bf16x8 __attribute__((ext_vector_type(8)));
typedef float f32x4 __attribute__((ext_vector_type(4)));
#define MFMA16(a,b,c) __builtin_amdgcn_mfma_f32_16x16x32_bf16(a,b,c,0,0,0)

__device__ __forceinline__ unsigned short f2bf(float f) {
    union { float f; unsigned u; } v; v.f = f;
    unsigned u = v.u;
    u += 0x7FFFu + ((u >> 16) & 1u);      // RTNE
    return (unsigned short)(u >> 16);
}
__device__ __forceinline__ float bf2f(unsigned short s) {
    union { unsigned u; float f; } v; v.u = ((unsigned)s) << 16; return v.f;
}
__device__ __forceinline__ unsigned cvtpk(float lo, float hi) {
    unsigned r;
    asm("v_cvt_pk_bf16_f32 %0, %1, %2" : "=v"(r) : "v"(lo), "v"(hi));
    return r;
}
__device__ __forceinline__ bf16x8 pack8(const float* p) {
    const float4 a = *(const float4*)p;
    const float4 b = *(const float4*)(p + 4);
    union { unsigned u[4]; bf16x8 v; } r;
    r.u[0] = cvtpk(a.x, a.y); r.u[1] = cvtpk(a.z, a.w);
    r.u[2] = cvtpk(b.x, b.y); r.u[3] = cvtpk(b.z, b.w);
    return r.v;
}
// swizzled flat index for [32][256] bf16 LDS tiles: XOR row bits into 8-col granule
__device__ __forceinline__ int qsw(int r, int c) {
    return r * 256 + (c ^ ((r & 7) << 3));
}

// ---------------------------------------------------------------------------
// Prep (read-coalesced): WT[768][256] <- [Wq|Wk|Wv]^T ; aW1T[128][256] ;
// WtClk[128][320] ; WtU[128][128] ; WtNid[128][128] ; WtNsem[128][320] ;
// projT[576][896]
// ---------------------------------------------------------------------------
#define PREP_TOTAL (196608 + 32768 + 40960 + 16384 + 16384 + 40960 + 516096)
__global__ __launch_bounds__(256) void prep_kernel(
    const float* __restrict__ Wq, const float* __restrict__ Wk,
    const float* __restrict__ Wv, const float* __restrict__ aW1,
    const float* __restrict__ clk_W1, const float* __restrict__ uagg_W1,
    const float* __restrict__ nid_W1, const float* __restrict__ nsem_W1,
    const float* __restrict__ proj_W,
    unsigned short* __restrict__ WT, unsigned short* __restrict__ aW1T,
    unsigned short* __restrict__ WtClk, unsigned short* __restrict__ WtU,
    unsigned short* __restrict__ WtNid, unsigned short* __restrict__ WtNsem,
    unsigned short* __restrict__ projT)
{
    int idx = blockIdx.x * 256 + threadIdx.x;
    if (idx < 65536) {
        int k = idx >> 8, n = idx & 255;
        WT[n * 256 + k] = f2bf(Wq[idx]);
    } else if (idx < 131072) {
        int s = idx - 65536; int k = s >> 8, n = s & 255;
        WT[(n + 256) * 256 + k] = f2bf(Wk[s]);
    } else if (idx < 196608) {
        int s = idx - 131072; int k = s >> 8, n = s & 255;
        WT[(n + 512) * 256 + k] = f2bf(Wv[s]);
    } else if (idx < 196608 + 32768) {
        int s = idx - 196608; int k = s >> 7, n = s & 127;
        aW1T[n * 256 + k] = f2bf(aW1[s]);
    } else if (idx < 229376 + 40960) {
        int s = idx - 229376; int k = s >> 7, n = s & 127;
        WtClk[n * 320 + k] = f2bf(clk_W1[s]);
    } else if (idx < 270336 + 16384) {
        int s = idx - 270336; int k = s >> 7, n = s & 127;
        WtU[n * 128 + k] = f2bf(uagg_W1[s]);
    } else if (idx < 286720 + 16384) {
        int s = idx - 286720; int k = s >> 7, n = s & 127;
        WtNid[n * 128 + k] = f2bf(nid_W1[s]);
    } else if (idx < 303104 + 40960) {
        int s = idx - 303104; int k = s >> 7, n = s & 127;
        WtNsem[n * 320 + k] = f2bf(nsem_W1[s]);
    } else if (idx < PREP_TOTAL) {
        int s = idx - 344064; int k = s / 576, n = s - k * 576;
        projT[(size_t)n * 896 + k] = f2bf(proj_W[s]);
    }
}

// ---------------------------------------------------------------------------
// tf_core: one block (4 waves) per sequence. LDS = 32768 B -> 4 blocks/CU.
// V held in registers (wave-local heads); Q/K in XOR-swizzled 16KB tiles.
// ---------------------------------------------------------------------------
__global__ __launch_bounds__(256, 4) void tf_core(
    const int* __restrict__ clicked_title, const int* __restrict__ clicked_topic,
    const int* __restrict__ candidate_title, const int* __restrict__ candidate_topic,
    const int* __restrict__ neighbor_title, const int* __restrict__ neighbor_topic,
    const float* __restrict__ word_emb, const float* __restrict__ topic_emb,
    const unsigned short* __restrict__ WT, const unsigned short* __restrict__ aW1T,
    const float* __restrict__ ab1, const float* __restrict__ aw2,
    unsigned short* __restrict__ sem)
{
    __shared__ __align__(16) unsigned short qo[32 * 256];   // Q, then O (swizzled)
    __shared__ __align__(16) unsigned short kp[32 * 256];   // K, then per-wave P; head reused for pls/pas

    float* pls_part = (float*)&kp[0];                // [4][32] after K/P dead
    float* pas_s    = (float*)&kp[0] + 128;          // [32]

    const int tid = threadIdx.x;
    const int l = tid & 63, w = tid >> 6;
    const int lm = l & 15, lg = l >> 4;
    const int rbase = lg * 4;
    const int kb = lg * 8;
    const int i = blockIdx.x;

    const int* tok; int topic;
    if (i < B_*C_)            { tok = clicked_title   + i*T_;               topic = clicked_topic[i]; }
    else if (i < B_*C_ + B_)  { int j = i - B_*C_;      tok = candidate_title + j*T_; topic = candidate_topic[j]; }
    else                      { int j = i - (B_*C_+B_); tok = neighbor_title  + j*T_; topic = neighbor_topic[j]; }

    // ---- A-fragments of x (rows 30/31 zero) ----
    bf16x8 afrag[2][8];
    #pragma unroll
    for (int mt = 0; mt < 2; ++mt) {
        int row = mt * 16 + lm;
        if (row < T_) {
            const float* xr = word_emb + (size_t)tok[row] * D_;
            #pragma unroll
            for (int kt = 0; kt < 8; ++kt)
                afrag[mt][kt] = pack8(xr + kt * 32 + kb);
        } else {
            #pragma unroll
            for (int kt = 0; kt < 8; ++kt) {
                bf16x8 z;
                #pragma unroll
                for (int e = 0; e < 8; ++e) z[e] = 0;
                afrag[mt][kt] = z;
            }
        }
    }

    // ---- QKV: wave w produces Q/K/V cols [64w..64w+63] (12 tiles) ----
    // V tiles stay in registers as packed bf16 row-pairs.
    unsigned vpk[4][4];
    #pragma unroll
    for (int t = 0; t < 12; ++t) {
        const int kind = t >> 2, tt = t & 3;          // kind 0=Q 1=K 2=V
        const int n0 = (kind << 8) + 64 * w + 16 * tt;
        const unsigned short* wp = WT + (size_t)(n0 + lm) * 256 + kb;
        f32x4 acc0 = {0.f,0.f,0.f,0.f}, acc1 = {0.f,0.f,0.f,0.f};
        #pragma unroll
        for (int kt = 0; kt < 8; ++kt) {
            bf16x8 b = *(const bf16x8*)(wp + kt * 32);
            acc0 = MFMA16(afrag[0][kt], b, acc0);
            acc1 = MFMA16(afrag[1][kt], b, acc1);
        }
        const int lc = 64 * w + 16 * tt + lm;          // col within Q/K matrix
        if (kind == 0) {
            #pragma unroll
            for (int r = 0; r < 4; ++r) {
                qo[qsw(rbase + r, lc)]      = f2bf(acc0[r]);
                qo[qsw(16 + rbase + r, lc)] = f2bf(acc1[r]);
            }
        } else if (kind == 1) {
            #pragma unroll
            for (int r = 0; r < 4; ++r) {
                kp[qsw(rbase + r, lc)]      = f2bf(acc0[r]);
                kp[qsw(16 + rbase + r, lc)] = f2bf(acc1[r]);
            }
        } else {
            vpk[tt][0] = cvtpk(acc0[0], acc0[1]);      // V rows rbase, rbase+1
            vpk[tt][1] = cvtpk(acc0[2], acc0[3]);      // rows rbase+2, +3
            vpk[tt][2] = cvtpk(acc1[0], acc1[1]);      // rows 16+rbase..
            vpk[tt][3] = cvtpk(acc1[2], acc1[3]);
        }
    }
    // no barrier needed: Q/K/V/P are all wave-private from here to pooling

    // ---- Attention: 2 heads/wave; P reuses dead K cols [64w..64w+31] ----
    const float sc = 0.17677669529663687f;   // 1/sqrt(32)
    const int pcb = 64 * w;
    const int s0l = lm + ((lg & 1) << 5);    // V-shfl source lanes
    const int s1l = s0l + 16;
    const bool useB = (lg >> 1) != 0;
    #pragma unroll
    for (int hh = 0; hh < 2; ++hh) {
        const int cb = 64 * w + 32 * hh;
        bf16x8 aq0 = *(const bf16x8*)&qo[qsw(lm, cb + kb)];
        bf16x8 aq1 = *(const bf16x8*)&qo[qsw(16 + lm, cb + kb)];
        bf16x8 bk0 = *(const bf16x8*)&kp[qsw(lm, cb + kb)];
        bf16x8 bk1 = *(const bf16x8*)&kp[qsw(16 + lm, cb + kb)];
        f32x4 z = {0.f,0.f,0.f,0.f};
        f32x4 s00 = MFMA16(aq0, bk0, z);
        f32x4 s01 = MFMA16(aq0, bk1, z);
        f32x4 s10 = MFMA16(aq1, bk0, z);
        f32x4 s11 = MFMA16(aq1, bk1, z);
        #pragma unroll
        for (int r = 0; r < 4; ++r) {
            s00[r] *= sc; s01[r] *= sc; s10[r] *= sc; s11[r] *= sc;
            if (lm >= 14) { s01[r] = -1e30f; s11[r] = -1e30f; }   // keys 30,31
        }
        #pragma unroll
        for (int r = 0; r < 4; ++r) {
            float mx0 = fmaxf(s00[r], s01[r]);
            float mx1 = fmaxf(s10[r], s11[r]);
            #pragma unroll
            for (int d = 1; d < 16; d <<= 1) {
                mx0 = fmaxf(mx0, __shfl_xor(mx0, d));
                mx1 = fmaxf(mx1, __shfl_xor(mx1, d));
            }
            float e00 = __expf(s00[r] - mx0), e01 = __expf(s01[r] - mx0);
            float e10 = __expf(s10[r] - mx1), e11 = __expf(s11[r] - mx1);
            float sm0 = e00 + e01, sm1 = e10 + e11;
            #pragma unroll
            for (int d = 1; d < 16; d <<= 1) {
                sm0 += __shfl_xor(sm0, d);
                sm1 += __shfl_xor(sm1, d);
            }
            float inv0 = 1.f / sm0, inv1 = 1.f / sm1;
            kp[qsw(rbase + r, pcb + lm)]           = f2bf(e00 * inv0);
            kp[qsw(rbase + r, pcb + 16 + lm)]      = f2bf(e01 * inv0);
            kp[qsw(16 + rbase + r, pcb + lm)]      = f2bf(e10 * inv1);
            kp[qsw(16 + rbase + r, pcb + 16 + lm)] = f2bf(e11 * inv1);
        }
        bf16x8 ap0 = *(const bf16x8*)&kp[qsw(lm, pcb + kb)];
        bf16x8 ap1 = *(const bf16x8*)&kp[qsw(16 + lm, pcb + kb)];
        // V B-fragments from registers via lg-group redistribution
        union { unsigned u[4]; bf16x8 v; } bv0, bv1;
        {
            unsigned a0 = __shfl(vpk[2*hh][0], s0l), a1 = __shfl(vpk[2*hh][1], s0l);
            unsigned b0 = __shfl(vpk[2*hh][2], s0l), b1 = __shfl(vpk[2*hh][3], s0l);
            unsigned a2 = __shfl(vpk[2*hh][0], s1l), a3 = __shfl(vpk[2*hh][1], s1l);
            unsigned b2 = __shfl(vpk[2*hh][2], s1l), b3 = __shfl(vpk[2*hh][3], s1l);
            bv0.u[0] = useB ? b0 : a0; bv0.u[1] = useB ? b1 : a1;
            bv0.u[2] = useB ? b2 : a2; bv0.u[3] = useB ? b3 : a3;
        }
        {
            unsigned a0 = __shfl(vpk[2*hh+1][0], s0l), a1 = __shfl(vpk[2*hh+1][1], s0l);
            unsigned b0 = __shfl(vpk[2*hh+1][2], s0l), b1 = __shfl(vpk[2*hh+1][3], s0l);
            unsigned a2 = __shfl(vpk[2*hh+1][0], s1l), a3 = __shfl(vpk[2*hh+1][1], s1l);
            unsigned b2 = __shfl(vpk[2*hh+1][2], s1l), b3 = __shfl(vpk[2*hh+1][3], s1l);
            bv1.u[0] = useB ? b0 : a0; bv1.u[1] = useB ? b1 : a1;
            bv1.u[2] = useB ? b2 : a2; bv1.u[3] = useB ? b3 : a3;
        }
        f32x4 o00 = MFMA16(ap0, bv0.v, z);
        f32x4 o01 = MFMA16(ap0, bv1.v, z);
        f32x4 o10 = MFMA16(ap1, bv0.v, z);
        f32x4 o11 = MFMA16(ap1, bv1.v, z);
        #pragma unroll
        for (int r = 0; r < 4; ++r) {
            qo[qsw(rbase + r, cb + lm)]           = f2bf(o00[r]);
            qo[qsw(rbase + r, cb + 16 + lm)]      = f2bf(o01[r]);
            qo[qsw(16 + rbase + r, cb + lm)]      = f2bf(o10[r]);
            qo[qsw(16 + rbase + r, cb + 16 + lm)] = f2bf(o11[r]);
        }
    }
    __syncthreads();   // O complete; K/P dead -> pls region reusable

    // ---- Pooling GEMM: wave w -> hidden cols [32w..32w+31] ----
    {
        f32x4 h00 = {0.f,0.f,0.f,0.f}, h01 = h00, h10 = h00, h11 = h00;
        const unsigned short* w0p = aW1T + (size_t)(w * 32 + lm) * 256 + kb;
        const unsigned short* w1p = aW1T + (size_t)(w * 32 + 16 + lm) * 256 + kb;
        #pragma unroll
        for (int kt = 0; kt < 8; ++kt) {
            bf16x8 ao0 = *(const bf16x8*)&qo[qsw(lm, kt * 32 + kb)];
            bf16x8 ao1 = *(const bf16x8*)&qo[qsw(16 + lm, kt * 32 + kb)];
            bf16x8 bw0 = *(const bf16x8*)(w0p + kt * 32);
            bf16x8 bw1 = *(const bf16x8*)(w1p + kt * 32);
            h00 = MFMA16(ao0, bw0, h00);
            h01 = MFMA16(ao0, bw1, h01);
            h10 = MFMA16(ao1, bw0, h10);
            h11 = MFMA16(ao1, bw1, h11);
        }
        const int c0 = w * 32 + lm, c1 = c0 + 16;
        const float b0 = ab1[c0], b1 = ab1[c1];
        const float a20 = aw2[c0], a21 = aw2[c1];
        float vsum[4];
        #pragma unroll
        for (int r = 0; r < 4; ++r) {
            float v0 = tanhf(h00[r] + b0) * a20 + tanhf(h01[r] + b1) * a21;
            float v1 = tanhf(h10[r] + b0) * a20 + tanhf(h11[r] + b1) * a21;
            #pragma unroll
            for (int d = 1; d < 16; d <<= 1) {
                v0 += __shfl_xor(v0, d);
                v1 += __shfl_xor(v1, d);
            }
            vsum[r] = v0;
            if (lm == 0) pls_part[w * 32 + 16 + rbase + r] = v1;
        }
        #pragma unroll
        for (int r = 0; r < 4; ++r)
            if (lm == 0) pls_part[w * 32 + rbase + r] = __shfl(vsum[r], lg * 16);
    }
    __syncthreads();

    // ---- final softmax over 30 (wave 0) ----
    if (w == 0) {
        float pl = -1e30f;
        if (l < T_) pl = pls_part[l] + pls_part[32 + l] + pls_part[64 + l] + pls_part[96 + l];
        float m = pl;
        #pragma unroll
        for (int d = 1; d < 64; d <<= 1) m = fmaxf(m, __shfl_xor(m, d));
        float e = (l < T_) ? __expf(pl - m) : 0.f;
        float s = e;
        #pragma unroll
        for (int d = 1; d < 64; d <<= 1) s += __shfl_xor(s, d);
        if (l < 32) pas_s[l] = e / s;
    }
    __syncthreads();

    // ---- title = pa @ o (bf16 out); concat topic ----
    {
        float acc = 0.f;
        #pragma unroll 6
        for (int r = 0; r < T_; ++r) acc += pas_s[r] * bf2f(qo[qsw(r, tid)]);
        sem[(size_t)i * SEM_ + tid] = f2bf(acc);
    }
    if (tid < TD_) sem[(size_t)i * SEM_ + D_ + tid] = f2bf(topic_emb[(size_t)topic * TD_ + tid]);
}

// ---------------------------------------------------------------------------
// Batched additive-attention logits (unchanged)
// ---------------------------------------------------------------------------
template<int DIM, bool XBF>
__device__ __forceinline__ void agg_tile(
    const void* xrow_lane, const unsigned short* __restrict__ Wt,
    const float* __restrict__ b1, const float* __restrict__ w2, float b2,
    const int* __restrict__ maskp, int item0, float* __restrict__ logits,
    int lm, int lg)
{
    constexpr int KT = DIM / 32;
    const int kb = lg * 8;
    bf16x8 a[KT];
    if (XBF) {
        const unsigned short* xr = (const unsigned short*)xrow_lane;
        #pragma unroll
        for (int kt = 0; kt < KT; ++kt) a[kt] = *(const bf16x8*)(xr + kt * 32 + kb);
    } else {
        const float* xr = (const float*)xrow_lane;
        #pragma unroll
        for (int kt = 0; kt < KT; ++kt) a[kt] = pack8(xr + kt * 32 + kb);
    }
    float vs[4] = {0.f, 0.f, 0.f, 0.f};
    #pragma unroll
    for (int nt = 0; nt < 8; ++nt) {
        const unsigned short* wp = Wt + (size_t)(nt * 16 + lm) * DIM + kb;
        f32x4 acc = {0.f,0.f,0.f,0.f};
        #pragma unroll
        for (int kt = 0; kt < KT; ++kt)
            acc = MFMA16(a[kt], *(const bf16x8*)(wp + kt * 32), acc);
        float b1v = b1[nt * 16 + lm], w2v = w2[nt * 16 + lm];
        vs[0] += tanhf(acc[0] + b1v) * w2v;
        vs[1] += tanhf(acc[1] + b1v) * w2v;
        vs[2] += tanhf(acc[2] + b1v) * w2v;
        vs[3] += tanhf(acc[3] + b1v) * w2v;
    }
    #pragma unroll
    for (int d = 1; d < 16; d <<= 1) {
        vs[0] += __shfl_xor(vs[0], d); vs[1] += __shfl_xor(vs[1], d);
        vs[2] += __shfl_xor(vs[2], d); vs[3] += __shfl_xor(vs[3], d);
    }
    if (lm == 0) {
        #pragma unroll
        for (int r = 0; r < 4; ++r) {
            int item = item0 + lg * 4 + r;
            logits[item] = maskp[item] ? (vs[r] + b2) : -1e30f;
        }
    }
}

__global__ __launch_bounds__(256) void agg_logits_kernel(
    const unsigned short* __restrict__ sem,
    const float* __restrict__ user_emb, const float* __restrict__ news_emb,
    const int* __restrict__ neighbor_users, const int* __restrict__ neighbor_news,
    const int* __restrict__ clicked_mask, const int* __restrict__ neighbor_user_mask,
    const int* __restrict__ neighbor_news_mask,
    const unsigned short* __restrict__ WtClk, const unsigned short* __restrict__ WtU,
    const unsigned short* __restrict__ WtNid, const unsigned short* __restrict__ WtNsem,
    const float* __restrict__ clk_b1, const float* __restrict__ clk_w2, const float* __restrict__ clk_b2,
    const float* __restrict__ uagg_b1, const float* __restrict__ uagg_w2, const float* __restrict__ uagg_b2,
    const float* __restrict__ nid_b1, const float* __restrict__ nid_w2, const float* __restrict__ nid_b2,
    const float* __restrict__ nsem_b1, const float* __restrict__ nsem_w2, const float* __restrict__ nsem_b2,
    float* __restrict__ lg_clk, float* __restrict__ lg_u,
    float* __restrict__ lg_nid, float* __restrict__ lg_nsem)
{
    const int tid = threadIdx.x;
    const int l = tid & 63, w = tid >> 6;
    const int lm = l & 15, lg = l >> 4;
    const int gid = blockIdx.x * 4 + w;

    if (gid < 400) {
        int item0 = gid * 16;
        const unsigned short* xr = sem + (size_t)(item0 + lm) * SEM_;
        agg_tile<320, true>(xr, WtClk, clk_b1, clk_w2, clk_b2[0],
                            clicked_mask, item0, lg_clk, lm, lg);
    } else if (gid < 520) {
        int item0 = (gid - 400) * 16;
        const float* xr = user_emb + (size_t)neighbor_users[item0 + lm] * 128;
        agg_tile<128, false>(xr, WtU, uagg_b1, uagg_w2, uagg_b2[0],
                             neighbor_user_mask, item0, lg_u, lm, lg);
    } else if (gid < 640) {
        int item0 = (gid - 520) * 16;
        const float* xr = news_emb + (size_t)neighbor_news[item0 + lm] * 128;
        agg_tile<128, false>(xr, WtNid, nid_b1, nid_w2, nid_b2[0],
                             neighbor_news_mask, item0, lg_nid, lm, lg);
    } else {
        int item0 = (gid - 640) * 16;
        const unsigned short* xr = sem + (size_t)(6528 + item0 + lm) * SEM_;
        agg_tile<320, true>(xr, WtNsem, nsem_b1, nsem_w2, nsem_b2[0],
                            neighbor_news_mask, item0, lg_nsem, lm, lg);
    }
}

__device__ __forceinline__ float softmax_lane(float v, bool valid) {
    float m = v;
    #pragma unroll
    for (int d = 1; d < 64; d <<= 1) m = fmaxf(m, __shfl_xor(m, d));
    float e = valid ? __expf(v - m) : 0.f;
    float s = e;
    #pragma unroll
    for (int d = 1; d < 64; d <<= 1) s += __shfl_xor(s, d);
    return e / s;
}

// ---------------------------------------------------------------------------
// finals: blocks 0..127 user branch -> out[:, :576];
//         blocks 128..255 news branch -> cat[896] bf16.
// sem rows staged in LDS to kill serial L2 chains.
// ---------------------------------------------------------------------------
__global__ __launch_bounds__(896) void finals_kernel(
    const float* __restrict__ lg_clk, const float* __restrict__ lg_u,
    const float* __restrict__ lg_nid, const float* __restrict__ lg_nsem,
    const unsigned short* __restrict__ sem,
    const float* __restrict__ user_emb, const float* __restrict__ news_emb,
    const int* __restrict__ user_id, const int* __restrict__ neighbor_users,
    const int* __restrict__ candidate_news_id, const int* __restrict__ neighbor_news,
    float* __restrict__ out, unsigned short* __restrict__ cat)
{
    const int tid = threadIdx.x, w = tid >> 6, l = tid & 63;
    __shared__ unsigned short ls[C_ * SEM_];   // 32000 B staging
    __shared__ float a0s[C_];
    __shared__ float a1s[NU_ + 1];

    if (blockIdx.x < B_) {
        const int b = blockIdx.x;
        // stage 50 sem rows (coalesced 16B)
        for (int idx = tid; idx < C_ * (SEM_ / 8); idx += 896) {
            int r = idx / 40, g = idx - r * 40;
            *(uint4*)&ls[r * SEM_ + g * 8] =
                *(const uint4*)&sem[(size_t)(b * C_ + r) * SEM_ + g * 8];
        }
        if (w == 0) {
            float v = (l < C_) ? lg_clk[b * C_ + l] : -1e30f;
            float a = softmax_lane(v, l < C_);
            if (l < C_) a0s[l] = a;
        } else if (w == 1) {
            float v = (l < NU_) ? lg_u[b * NU_ + l] : -1e30f;
            float a = softmax_lane(v, l < NU_);
            if (l < NU_) a1s[l] = a;
        }
        __syncthreads();
        if (tid < SEM_) {
            float acc = 0.f;
            #pragma unroll 5
            for (int c = 0; c < C_; ++c)
                acc += a0s[c] * bf2f(ls[c * SEM_ + tid]);
            out[(size_t)b * 576 + tid] = acc;
        } else if (tid < 448) {
            int d = tid - SEM_;
            out[(size_t)b * 576 + tid] = user_emb[(size_t)user_id[b] * 128 + d];
        } else if (tid < 576) {
            int d = tid - 448;
            float acc = 0.f;
            #pragma unroll
            for (int n = 0; n < NU_; ++n)
                acc += a1s[n] * user_emb[(size_t)neighbor_users[b * NU_ + n] * 128 + d];
            out[(size_t)b * 576 + 448 + d] = acc;
        }
    } else {
        const int b = blockIdx.x - B_;
        // stage 15 nsem rows
        for (int idx = tid; idx < NN_ * (SEM_ / 8); idx += 896) {
            int r = idx / 40, g = idx - r * 40;
            *(uint4*)&ls[r * SEM_ + g * 8] =
                *(const uint4*)&sem[(size_t)(6528 + b * NN_ + r) * SEM_ + g * 8];
        }
        if (w == 0) {
            float v = (l < NN_) ? lg_nid[b * NN_ + l] : -1e30f;
            float a = softmax_lane(v, l < NN_);
            if (l < NN_) a0s[l] = a;
        } else if (w == 1) {
            float v = (l < NN_) ? lg_nsem[b * NN_ + l] : -1e30f;
            float a = softmax_lane(v, l < NN_);
            if (l < NN_) a1s[l] = a;
        }
        __syncthreads();
        unsigned short* cp = cat + (size_t)b * 896;
        if (tid < SEM_) {
            cp[tid] = sem[(size_t)(B_*C_ + b) * SEM_ + tid];
        } else if (tid < 448) {
            int d = tid - SEM_;
            cp[tid] = f2bf(news_emb[(size_t)candidate_news_id[b] * 128 + d]);
        } else if (tid < 576) {
            int d = tid - 448;
            float acc = 0.f;
            #pragma unroll
            for (int n = 0; n < NN_; ++n)
                acc += a0s[n] * news_emb[(size_t)neighbor_news[b * NN_ + n] * 128 + d];
            cp[tid] = f2bf(acc);
        } else {
            int d = tid - 576;
            float acc = 0.f;
            #pragma unroll
            for (int n = 0; n < NN_; ++n)
                acc += a1s[n] * bf2f(ls[n * SEM_ + d]);
            cp[tid] = f2bf(acc);
        }
    }
}

// ---------------------------------------------------------------------------
// proj: news_repr = cat[128x896] @ proj_W + b  (288 wave-tiles)
// ---------------------------------------------------------------------------
__global__ __launch_bounds__(256) void proj_kernel(
    const unsigned short* __restrict__ cat, const unsigned short* __restrict__ projT,
    const float* __restrict__ proj_b, float* __restrict__ outp)
{
    const int tid = threadIdx.x;
    const int l = tid & 63, w = tid >> 6;
    const int lm = l & 15, lg = l >> 4;
    const int id = blockIdx.x * 4 + w;          // 0..287
    const int mt = id / 36, nt = id - mt * 36;
    const int kb = lg * 8;

    const unsigned short* ap = cat + (size_t)(mt * 16 + lm) * 896 + kb;
    const unsigned short* bp = projT + (size_t)(nt * 16 + lm) * 896 + kb;
    f32x4 acc = {0.f,0.f,0.f,0.f};
    #pragma unroll 7
    for (int kt = 0; kt < 28; ++kt)
        acc = MFMA16(*(const bf16x8*)(ap + kt * 32), *(const bf16x8*)(bp + kt * 32), acc);

    const int coln = nt * 16 + lm;
    const float pb = proj_b[coln];
    #pragma unroll
    for (int r = 0; r < 4; ++r) {
        int row = mt * 16 + lg * 4 + r;
        outp[(size_t)row * 576 + coln] = acc[r] + pb;
    }
}

extern "C" void kernel_launch(void* const* d_in, const int* in_sizes, int n_in,
                              void* d_out, int out_size, void* d_ws, size_t ws_size,
                              hipStream_t stream)
{
    const int* user_id            = (const int*)d_in[0];
    const int* candidate_news_id  = (const int*)d_in[1];
    const int* candidate_title    = (const int*)d_in[2];
    const int* candidate_topic    = (const int*)d_in[3];
    const int* clicked_title      = (const int*)d_in[4];
    const int* clicked_topic      = (const int*)d_in[5];
    const int* clicked_mask       = (const int*)d_in[6];
    const int* neighbor_users     = (const int*)d_in[7];
    const int* neighbor_user_mask = (const int*)d_in[8];
    const int* neighbor_news      = (const int*)d_in[9];
    const int* neighbor_news_mask = (const int*)d_in[10];
    const int* neighbor_title     = (const int*)d_in[11];
    const int* neighbor_topic     = (const int*)d_in[12];
    const float* user_emb  = (const float*)d_in[13];
    const float* news_emb  = (const float*)d_in[14];
    const float* word_emb  = (const float*)d_in[15];
    const float* topic_emb = (const float*)d_in[16];
    const float* Wq  = (const float*)d_in[17];
    const float* Wk  = (const float*)d_in[18];
    const float* Wv  = (const float*)d_in[19];
    const float* aW1 = (const float*)d_in[20];
    const float* ab1 = (const float*)d_in[21];
    const float* aw2 = (const float*)d_in[22];
    const float* clk_W1 = (const float*)d_in[23];
    const float* clk_b1 = (const float*)d_in[24];
    const float* clk_w2 = (const float*)d_in[25];
    const float* clk_b2 = (const float*)d_in[26];
    const float* uagg_W1 = (const float*)d_in[27];
    const float* uagg_b1 = (const float*)d_in[28];
    const float* uagg_w2 = (const float*)d_in[29];
    const float* uagg_b2 = (const float*)d_in[30];
    const float* nid_W1 = (const float*)d_in[31];
    const float* nid_b1 = (const float*)d_in[32];
    const float* nid_w2 = (const float*)d_in[33];
    const float* nid_b2 = (const float*)d_in[34];
    const float* nsem_W1 = (const float*)d_in[35];
    const float* nsem_b1 = (const float*)d_in[36];
    const float* nsem_w2 = (const float*)d_in[37];
    const float* nsem_b2 = (const float*)d_in[38];
    const float* proj_W = (const float*)d_in[39];
    const float* proj_b = (const float*)d_in[40];

    // ---- workspace layout ----
    char* p = (char*)d_ws;
    unsigned short* sem    = (unsigned short*)p; p += (size_t)NSEQ_ * SEM_ * 2;
    unsigned short* WT     = (unsigned short*)p; p += 768 * 256 * 2;
    unsigned short* aW1T   = (unsigned short*)p; p += 128 * 256 * 2;
    unsigned short* WtClk  = (unsigned short*)p; p += 128 * 320 * 2;
    unsigned short* WtU    = (unsigned short*)p; p += 128 * 128 * 2;
    unsigned short* WtNid  = (unsigned short*)p; p += 128 * 128 * 2;
    unsigned short* WtNsem = (unsigned short*)p; p += 128 * 320 * 2;
    unsigned short* projT  = (unsigned short*)p; p += 576 * 896 * 2;
    float* lg_clk  = (float*)p; p += 6400 * 4;
    float* lg_u    = (float*)p; p += 1920 * 4;
    float* lg_nid  = (float*)p; p += 1920 * 4;
    float* lg_nsem = (float*)p; p += 1920 * 4;
    unsigned short* cat = (unsigned short*)p; p += 128 * 896 * 2;

    prep_kernel<<<(PREP_TOTAL + 255) / 256, 256, 0, stream>>>(
        Wq, Wk, Wv, aW1, clk_W1, uagg_W1, nid_W1, nsem_W1, proj_W,
        WT, aW1T, WtClk, WtU, WtNid, WtNsem, projT);

    tf_core<<<NSEQ_, 256, 0, stream>>>(clicked_title, clicked_topic,
        candidate_title, candidate_topic, neighbor_title, neighbor_topic,
        word_emb, topic_emb, WT, aW1T, ab1, aw2, sem);

    agg_logits_kernel<<<190, 256, 0, stream>>>(sem, user_emb, news_emb,
        neighbor_users, neighbor_news,
        clicked_mask, neighbor_user_mask, neighbor_news_mask,
        WtClk, WtU, WtNid, WtNsem,
        clk_b1, clk_w2, clk_b2, uagg_b1, uagg_w2, uagg_b2,
        nid_b1, nid_w2, nid_b2, nsem_b1, nsem_w2, nsem_b2,
        lg_clk, lg_u, lg_nid, lg_nsem);

    finals_kernel<<<256, 896, 0, stream>>>(lg_clk, lg_u, lg_nid, lg_nsem,
        sem, user_emb, news_emb, user_id, neighbor_users,
        candidate_news_id, neighbor_news,
        (float*)d_out, cat);

    proj_kernel<<<72, 256, 0, stream>>>(cat, projT, proj_b,
        (float*)d_out + (size_t)B_ * 576);
}